// Round 5
// baseline (37946.420 us; speedup 1.0000x reference)
//
#include <hip/hip_runtime.h>

#define TPB   512
#define NBLK  256
#define UNITS 32
#define HID   1024

static_assert(NBLK * TPB == 131072, "grid must cover batch exactly");

// Issue loads of W1T row J (LDS) and W2 row J (global/L2) into register buffers.
#define PREF(R, V, BJ, J) {                                              \
    const float4* _w1 = (const float4*)(sW1T + (J) * UNITS);             \
    const float4* _w2 = W2r + (J) * 8;                                   \
    _Pragma("unroll")                                                    \
    for (int q = 0; q < 8; ++q) R[q] = _w1[q];                           \
    _Pragma("unroll")                                                    \
    for (int q = 0; q < 8; ++q) V[q] = _w2[q];                           \
    BJ = sb1[J];                                                         \
}

// fwd: h_j = zc.W1col_j + b1_j ; yg += relu(h_j) * W2row_j
#define FWD_BODY(R, V, BJ) {                                             \
    float p0 = 0.f, p1 = 0.f, p2 = 0.f, p3 = 0.f;                        \
    _Pragma("unroll")                                                    \
    for (int q = 0; q < 8; ++q) {                                        \
        p0 = fmaf(zc[4*q+0], R[q].x, p0);                                \
        p1 = fmaf(zc[4*q+1], R[q].y, p1);                                \
        p2 = fmaf(zc[4*q+2], R[q].z, p2);                                \
        p3 = fmaf(zc[4*q+3], R[q].w, p3);                                \
    }                                                                    \
    float h = ((p0 + p1) + (p2 + p3)) + BJ;                              \
    float r = fmaxf(h, 0.f);                                             \
    _Pragma("unroll")                                                    \
    for (int q = 0; q < 8; ++q) {                                        \
        yg[4*q+0] = fmaf(r, V[q].x, yg[4*q+0]);                          \
        yg[4*q+1] = fmaf(r, V[q].y, yg[4*q+1]);                          \
        yg[4*q+2] = fmaf(r, V[q].z, yg[4*q+2]);                          \
        yg[4*q+3] = fmaf(r, V[q].w, yg[4*q+3]);                          \
    }                                                                    \
}

// bwd: recompute h_j; gr_j = g.W2row_j; k += (h>0 ? -gr : 0) * W1col_j
#define BWD_BODY(R, V, BJ) {                                             \
    float p0 = 0.f, p1 = 0.f, p2 = 0.f, p3 = 0.f;                        \
    float q0 = 0.f, q1 = 0.f, q2 = 0.f, q3 = 0.f;                        \
    _Pragma("unroll")                                                    \
    for (int q = 0; q < 8; ++q) {                                        \
        p0 = fmaf(zc[4*q+0], R[q].x, p0);                                \
        p1 = fmaf(zc[4*q+1], R[q].y, p1);                                \
        p2 = fmaf(zc[4*q+2], R[q].z, p2);                                \
        p3 = fmaf(zc[4*q+3], R[q].w, p3);                                \
        q0 = fmaf(yg[4*q+0], V[q].x, q0);                                \
        q1 = fmaf(yg[4*q+1], V[q].y, q1);                                \
        q2 = fmaf(yg[4*q+2], V[q].z, q2);                                \
        q3 = fmaf(yg[4*q+3], V[q].w, q3);                                \
    }                                                                    \
    float h  = ((p0 + p1) + (p2 + p3)) + BJ;                             \
    float gr = (q0 + q1) + (q2 + q3);                                    \
    float gh = (h > 0.f) ? -gr : 0.f;                                    \
    _Pragma("unroll")                                                    \
    for (int q = 0; q < 8; ++q) {                                        \
        k[4*q+0] = fmaf(gh, R[q].x, k[4*q+0]);                           \
        k[4*q+1] = fmaf(gh, R[q].y, k[4*q+1]);                           \
        k[4*q+2] = fmaf(gh, R[q].z, k[4*q+2]);                           \
        k[4*q+3] = fmaf(gh, R[q].w, k[4*q+3]);                           \
    }                                                                    \
}

__global__ __launch_bounds__(TPB, 2)
void hopfield_rk4_pipe(const float* __restrict__ x,  const float* __restrict__ W1,
                       const float* __restrict__ b1, const float* __restrict__ W2,
                       const float* __restrict__ b2, float* __restrict__ out) {
    // fp32 W1^T [j][u] in LDS (128 KB), broadcast reads. W2 from global (L2).
    __shared__ __align__(16) float sW1T[HID * UNITS];
    __shared__ float sb1[HID];

    const int tid = threadIdx.x;
    #pragma unroll 1
    for (int idx = tid; idx < UNITS * HID; idx += TPB) {
        int u = idx >> 10, j = idx & (HID - 1);
        sW1T[j * UNITS + u] = W1[idx];          // transpose [32][1024] -> [j][u]
    }
    #pragma unroll 1
    for (int j = tid; j < HID; j += TPB) sb1[j] = b1[j];
    __syncthreads();

    const long sample = (long)blockIdx.x * TPB + tid;
    float zb[UNITS];
    {
        const float4* xr = (const float4*)(x + sample * UNITS);
        #pragma unroll
        for (int q = 0; q < 8; ++q) {
            float4 v = xr[q];
            zb[4*q+0] = v.x; zb[4*q+1] = v.y; zb[4*q+2] = v.z; zb[4*q+3] = v.w;
        }
    }

    const float dt = 0.1f;
    const float4* W2r = (const float4*)W2;     // row j = W2r[j*8 .. j*8+7]
    const float4* b2r = (const float4*)b2;

    #pragma unroll 1
    for (int step = 0; step < 10; ++step) {
        float acc[UNITS], zc[UNITS];
        #pragma unroll
        for (int u = 0; u < UNITS; ++u) { acc[u] = 0.f; zc[u] = zb[u]; }

        #pragma unroll 1
        for (int sub = 0; sub < 4; ++sub) {
            float yg[UNITS];
            #pragma unroll
            for (int u = 0; u < UNITS; ++u) yg[u] = 0.f;

            // ---------- forward, ping-pong software pipeline ----------
            {
                float4 ra[8], va[8], rb[8], vb[8];
                float bja, bjb;
                PREF(ra, va, bja, 0)
                #pragma unroll 1
                for (int jj = 0; jj < HID; jj += 2) {
                    PREF(rb, vb, bjb, jj + 1)            // loads fly over body A
                    FWD_BODY(ra, va, bja)
                    PREF(ra, va, bja, (jj + 2) & (HID - 1))
                    FWD_BODY(rb, vb, bjb)
                }
            }

            // ---------- g = 8*y/||y|| (in place) ----------
            #pragma unroll
            for (int q = 0; q < 8; ++q) {
                float4 bv = b2r[q];
                yg[4*q+0] += bv.x; yg[4*q+1] += bv.y;
                yg[4*q+2] += bv.z; yg[4*q+3] += bv.w;
            }
            float n0 = 0.f, n1 = 0.f, n2 = 0.f, n3 = 0.f;
            #pragma unroll
            for (int u = 0; u < UNITS; u += 4) {
                n0 = fmaf(yg[u+0], yg[u+0], n0); n1 = fmaf(yg[u+1], yg[u+1], n1);
                n2 = fmaf(yg[u+2], yg[u+2], n2); n3 = fmaf(yg[u+3], yg[u+3], n3);
            }
            float s8 = 8.0f * rsqrtf((n0 + n1) + (n2 + n3));
            #pragma unroll
            for (int u = 0; u < UNITS; ++u) yg[u] *= s8;

            float k[UNITS];
            #pragma unroll
            for (int u = 0; u < UNITS; ++u) k[u] = 0.f;

            // ---------- backward, ping-pong software pipeline ----------
            {
                float4 ra[8], va[8], rb[8], vb[8];
                float bja, bjb;
                PREF(ra, va, bja, 0)
                #pragma unroll 1
                for (int jj = 0; jj < HID; jj += 2) {
                    PREF(rb, vb, bjb, jj + 1)
                    BWD_BODY(ra, va, bja)
                    PREF(ra, va, bja, (jj + 2) & (HID - 1))
                    BWD_BODY(rb, vb, bjb)
                }
            }

            // ---------- RK4 bookkeeping ----------
            float aw = (sub == 0 || sub == 3) ? 1.f : 2.f;
            #pragma unroll
            for (int u = 0; u < UNITS; ++u) acc[u] += aw * k[u];
            if (sub < 3) {
                float cw = (sub == 2) ? dt : 0.5f * dt;
                #pragma unroll
                for (int u = 0; u < UNITS; ++u) zc[u] = fmaf(cw, k[u], zb[u]);
            }
        }

        #pragma unroll
        for (int u = 0; u < UNITS; ++u) zb[u] = fmaf(dt * (1.f / 6.f), acc[u], zb[u]);
    }

    float4* orow = (float4*)(out + sample * UNITS);
    #pragma unroll
    for (int q = 0; q < 8; ++q) {
        float4 v;
        v.x = zb[4*q+0]; v.y = zb[4*q+1]; v.z = zb[4*q+2]; v.w = zb[4*q+3];
        orow[q] = v;
    }
}

extern "C" void kernel_launch(void* const* d_in, const int* in_sizes, int n_in,
                              void* d_out, int out_size, void* d_ws, size_t ws_size,
                              hipStream_t stream) {
    const float* x  = (const float*)d_in[0];
    const float* W1 = (const float*)d_in[1];
    const float* b1 = (const float*)d_in[2];
    const float* W2 = (const float*)d_in[3];
    const float* b2 = (const float*)d_in[4];
    float* out = (float*)d_out;
    hipLaunchKernelGGL(hopfield_rk4_pipe, dim3(NBLK), dim3(TPB), 0, stream,
                       x, W1, b1, W2, b2, out);
}

// Round 6
// 35324.750 us; speedup vs baseline: 1.0742x; 1.0742x over previous
//
#include <hip/hip_runtime.h>

#define TPB   512
#define NBLK  256
#define UNITS 32
#define HID   1024

static_assert(NBLK * TPB == 131072, "grid must cover batch exactly");

typedef __attribute__((ext_vector_type(2))) float f32x2;

// Packed fp32 ops (CDNA2+): full IEEE fp32 FMA/add/mul on a 64-bit VGPR pair.
__device__ __forceinline__ f32x2 pkfma(f32x2 a, f32x2 b, f32x2 c) {
    f32x2 d;
    asm("v_pk_fma_f32 %0, %1, %2, %3" : "=v"(d) : "v"(a), "v"(b), "v"(c));
    return d;
}
__device__ __forceinline__ f32x2 pkadd(f32x2 a, f32x2 b) {
    f32x2 d;
    asm("v_pk_add_f32 %0, %1, %2" : "=v"(d) : "v"(a), "v"(b));
    return d;
}
__device__ __forceinline__ f32x2 pkmul(f32x2 a, f32x2 b) {
    f32x2 d;
    asm("v_pk_mul_f32 %0, %1, %2" : "=v"(d) : "v"(a), "v"(b));
    return d;
}
__device__ __forceinline__ f32x2 mk2(float a, float b) { f32x2 r; r.x = a; r.y = b; return r; }

// Load a 32-float row (global W2 or LDS W1T) into 16 f32x2 regs via float4 loads.
#define LOAD_ROW(WD, PTR) {                                          \
    _Pragma("unroll")                                                \
    for (int _q = 0; _q < 8; ++_q) {                                 \
        float4 _t = (PTR)[_q];                                       \
        WD[2*_q]   = mk2(_t.x, _t.y);                                \
        WD[2*_q+1] = mk2(_t.z, _t.w);                                \
    }                                                                \
}

// fwd: h_j = zc.W1col_j + b1_j ; yg += relu(h_j) * W2row_j
#define FWD_BODY(WC, J) {                                            \
    f32x2 w1[16];                                                    \
    const float4* _w1p = (const float4*)(sW1T + (J) * UNITS);        \
    LOAD_ROW(w1, _w1p)                                               \
    f32x2 p0 = mk2(0.f,0.f), p1 = mk2(0.f,0.f);                      \
    f32x2 p2 = mk2(0.f,0.f), p3 = mk2(0.f,0.f);                      \
    _Pragma("unroll")                                                \
    for (int _q = 0; _q < 4; ++_q) {                                 \
        p0 = pkfma(zc2[4*_q+0], w1[4*_q+0], p0);                     \
        p1 = pkfma(zc2[4*_q+1], w1[4*_q+1], p1);                     \
        p2 = pkfma(zc2[4*_q+2], w1[4*_q+2], p2);                     \
        p3 = pkfma(zc2[4*_q+3], w1[4*_q+3], p3);                     \
    }                                                                \
    f32x2 _s = pkadd(pkadd(p0, p1), pkadd(p2, p3));                  \
    float _h = (_s.x + _s.y) + sb1[J];                               \
    float _r = fmaxf(_h, 0.f);                                       \
    f32x2 _rr = mk2(_r, _r);                                         \
    _Pragma("unroll")                                                \
    for (int _i = 0; _i < 16; ++_i) yg2[_i] = pkfma(_rr, WC[_i], yg2[_i]); \
}

// bwd: recompute h_j; gr_j = g.W2row_j; k += (h>0 ? -gr : 0) * W1col_j
#define BWD_BODY(WC, J) {                                            \
    f32x2 w1[16];                                                    \
    const float4* _w1p = (const float4*)(sW1T + (J) * UNITS);        \
    LOAD_ROW(w1, _w1p)                                               \
    f32x2 p0 = mk2(0.f,0.f), p1 = mk2(0.f,0.f);                      \
    f32x2 p2 = mk2(0.f,0.f), p3 = mk2(0.f,0.f);                      \
    f32x2 q0 = mk2(0.f,0.f), q1 = mk2(0.f,0.f);                      \
    f32x2 q2 = mk2(0.f,0.f), q3 = mk2(0.f,0.f);                      \
    _Pragma("unroll")                                                \
    for (int _q = 0; _q < 4; ++_q) {                                 \
        p0 = pkfma(zc2[4*_q+0], w1[4*_q+0], p0);                     \
        p1 = pkfma(zc2[4*_q+1], w1[4*_q+1], p1);                     \
        p2 = pkfma(zc2[4*_q+2], w1[4*_q+2], p2);                     \
        p3 = pkfma(zc2[4*_q+3], w1[4*_q+3], p3);                     \
        q0 = pkfma(yg2[4*_q+0], WC[4*_q+0], q0);                     \
        q1 = pkfma(yg2[4*_q+1], WC[4*_q+1], q1);                     \
        q2 = pkfma(yg2[4*_q+2], WC[4*_q+2], q2);                     \
        q3 = pkfma(yg2[4*_q+3], WC[4*_q+3], q3);                     \
    }                                                                \
    f32x2 _sp = pkadd(pkadd(p0, p1), pkadd(p2, p3));                 \
    f32x2 _sq = pkadd(pkadd(q0, q1), pkadd(q2, q3));                 \
    float _h  = (_sp.x + _sp.y) + sb1[J];                            \
    float _gr = _sq.x + _sq.y;                                       \
    float _gh = (_h > 0.f) ? -_gr : 0.f;                             \
    f32x2 _gg = mk2(_gh, _gh);                                       \
    _Pragma("unroll")                                                \
    for (int _i = 0; _i < 16; ++_i) k2[_i] = pkfma(_gg, w1[_i], k2[_i]); \
}

__global__ __launch_bounds__(TPB)
__attribute__((amdgpu_waves_per_eu(2, 2)))
void hopfield_rk4_pk(const float* __restrict__ x,  const float* __restrict__ W1,
                     const float* __restrict__ b1, const float* __restrict__ W2,
                     const float* __restrict__ b2, float* __restrict__ out) {
    // fp32 W1^T [j][u] in LDS (128 KB), uniform-address broadcast reads.
    // W2 from global (L1/L2-resident, one 128B line per row), ping-pong
    // prefetched one j ahead into registers.
    __shared__ __align__(16) float sW1T[HID * UNITS];
    __shared__ float sb1[HID];

    const int tid = threadIdx.x;
    #pragma unroll 1
    for (int idx = tid; idx < UNITS * HID; idx += TPB) {
        int u = idx >> 10, j = idx & (HID - 1);
        sW1T[j * UNITS + u] = W1[idx];          // transpose [32][1024] -> [j][u]
    }
    #pragma unroll 1
    for (int j = tid; j < HID; j += TPB) sb1[j] = b1[j];
    __syncthreads();

    const long sample = (long)blockIdx.x * TPB + tid;
    f32x2 zb2[16];
    {
        const float4* xr = (const float4*)(x + sample * UNITS);
        #pragma unroll
        for (int q = 0; q < 8; ++q) {
            float4 v = xr[q];
            zb2[2*q]   = mk2(v.x, v.y);
            zb2[2*q+1] = mk2(v.z, v.w);
        }
    }

    const float dt = 0.1f;
    const float4* W2r = (const float4*)W2;     // row j = W2r[j*8 .. j*8+7]
    const float4* b2r = (const float4*)b2;

    #pragma unroll 1
    for (int step = 0; step < 10; ++step) {
        f32x2 acc2[16], zc2[16];
        #pragma unroll
        for (int i = 0; i < 16; ++i) { acc2[i] = mk2(0.f, 0.f); zc2[i] = zb2[i]; }

        #pragma unroll 1
        for (int sub = 0; sub < 4; ++sub) {
            f32x2 yg2[16];
            #pragma unroll
            for (int i = 0; i < 16; ++i) yg2[i] = mk2(0.f, 0.f);

            // ---------- forward, W2 ping-pong ----------
            {
                f32x2 wa[16], wb[16];
                LOAD_ROW(wa, W2r)
                #pragma unroll 1
                for (int jj = 0; jj < HID; jj += 2) {
                    { const float4* _p = W2r + (jj + 1) * 8; LOAD_ROW(wb, _p) }
                    FWD_BODY(wa, jj)
                    { const float4* _p = W2r + (((jj + 2) & (HID - 1))) * 8; LOAD_ROW(wa, _p) }
                    FWD_BODY(wb, jj + 1)
                }
            }

            // ---------- g = 8*(y+b2)/||y+b2|| (in place) ----------
            {
                f32x2 n0 = mk2(0.f, 0.f), n1 = mk2(0.f, 0.f);
                #pragma unroll
                for (int q = 0; q < 8; ++q) {
                    float4 bv = b2r[q];
                    yg2[2*q]   = pkadd(yg2[2*q],   mk2(bv.x, bv.y));
                    yg2[2*q+1] = pkadd(yg2[2*q+1], mk2(bv.z, bv.w));
                    n0 = pkfma(yg2[2*q],   yg2[2*q],   n0);
                    n1 = pkfma(yg2[2*q+1], yg2[2*q+1], n1);
                }
                f32x2 nn = pkadd(n0, n1);
                float s8 = 8.0f * rsqrtf(nn.x + nn.y);
                f32x2 ss = mk2(s8, s8);
                #pragma unroll
                for (int i = 0; i < 16; ++i) yg2[i] = pkmul(ss, yg2[i]);
            }

            f32x2 k2[16];
            #pragma unroll
            for (int i = 0; i < 16; ++i) k2[i] = mk2(0.f, 0.f);

            // ---------- backward, W2 ping-pong ----------
            {
                f32x2 wa[16], wb[16];
                LOAD_ROW(wa, W2r)
                #pragma unroll 1
                for (int jj = 0; jj < HID; jj += 2) {
                    { const float4* _p = W2r + (jj + 1) * 8; LOAD_ROW(wb, _p) }
                    BWD_BODY(wa, jj)
                    { const float4* _p = W2r + (((jj + 2) & (HID - 1))) * 8; LOAD_ROW(wa, _p) }
                    BWD_BODY(wb, jj + 1)
                }
            }

            // ---------- RK4 bookkeeping ----------
            float aw = (sub == 0 || sub == 3) ? 1.f : 2.f;
            f32x2 aww = mk2(aw, aw);
            #pragma unroll
            for (int i = 0; i < 16; ++i) acc2[i] = pkfma(aww, k2[i], acc2[i]);
            if (sub < 3) {
                float cw = (sub == 2) ? dt : 0.5f * dt;
                f32x2 cww = mk2(cw, cw);
                #pragma unroll
                for (int i = 0; i < 16; ++i) zc2[i] = pkfma(cww, k2[i], zb2[i]);
            }
        }

        f32x2 c6 = mk2(dt * (1.f / 6.f), dt * (1.f / 6.f));
        #pragma unroll
        for (int i = 0; i < 16; ++i) zb2[i] = pkfma(c6, acc2[i], zb2[i]);
    }

    float4* orow = (float4*)(out + sample * UNITS);
    #pragma unroll
    for (int q = 0; q < 8; ++q) {
        float4 v;
        v.x = zb2[2*q].x; v.y = zb2[2*q].y;
        v.z = zb2[2*q+1].x; v.w = zb2[2*q+1].y;
        orow[q] = v;
    }
}

extern "C" void kernel_launch(void* const* d_in, const int* in_sizes, int n_in,
                              void* d_out, int out_size, void* d_ws, size_t ws_size,
                              hipStream_t stream) {
    const float* x  = (const float*)d_in[0];
    const float* W1 = (const float*)d_in[1];
    const float* b1 = (const float*)d_in[2];
    const float* W2 = (const float*)d_in[3];
    const float* b2 = (const float*)d_in[4];
    float* out = (float*)d_out;
    hipLaunchKernelGGL(hopfield_rk4_pk, dim3(NBLK), dim3(TPB), 0, stream,
                       x, W1, b1, W2, b2, out);
}

// Round 7
// 6057.653 us; speedup vs baseline: 6.2642x; 5.8314x over previous
//
#include <hip/hip_runtime.h>

typedef _Float16 f16;
typedef __attribute__((ext_vector_type(8))) _Float16 f16x8;
typedef __attribute__((ext_vector_type(2))) _Float16 f16x2;
typedef __attribute__((ext_vector_type(16))) float f32x16;
typedef unsigned int u32;
typedef unsigned short u16;

#define UNITS 32
#define HID   1024
#define NCH   32      // 32 chunks of 32 j
#define TPB   256     // 4 waves
#define WPB   4
#define SPB   128     // samples per block (4 waves x 32)
#define NBLK  1024

static_assert(NBLK * SPB == 131072, "grid covers batch");

// Bank-swizzled byte offset of f16 (row, col) inside a 2KB [32][32] slice.
// 16B chunk id = col>>3, xor'd with row bits so 32 rows @ same col-chunk
// spread over all 8 chunk positions (4-way = data floor on b128 reads).
__device__ __forceinline__ int swz_off(int row, int col) {
    return row * 64 + ((((col >> 3) ^ ((row >> 1) & 3))) << 4) + ((col & 7) << 1);
}

// d_ws: 8 f16 arrays of 32768 elems (64KB each), each [32 chunks][2KB slice]:
// 0 W1jm_hi [c][jl][u]  (B of GEMM1: H = Z@W1)
// 1 W1jm_lo
// 2 X2T_hi  [c][u][jl]  (B of GEMM2: Y = R@W2)
// 3 X2T_lo
// 4 W2n_hi  [c][jl][u]  (B of GEMM4: GR = G@W2T)
// 5 W2n_lo
// 6 X1N_hi  [c][u][jl]  (B of GEMM5: K = M@W1T)
// 7 X1N_lo
__global__ void prep_weights(const float* __restrict__ W1,
                             const float* __restrict__ W2,
                             f16* __restrict__ ws) {
    int idx = blockIdx.x * 256 + threadIdx.x;   // 0..32767
    int c = idx >> 10, rem = idx & 1023;
    int jl = rem >> 5, u = rem & 31;
    int j = c * 32 + jl;
    float w1 = W1[u * HID + j];
    f16 h1 = (f16)w1;
    f16 l1 = (f16)((w1 - (float)h1) * 4096.0f);
    float w2 = W2[j * UNITS + u];
    f16 h2 = (f16)w2;
    f16 l2 = (f16)((w2 - (float)h2) * 4096.0f);
    char* p = (char*)ws;
    int oju = c * 2048 + swz_off(jl, u);
    int ouj = c * 2048 + swz_off(u, jl);
    *(f16*)(p + 0 * 65536 + oju) = h1;
    *(f16*)(p + 1 * 65536 + oju) = l1;
    *(f16*)(p + 2 * 65536 + ouj) = h2;
    *(f16*)(p + 3 * 65536 + ouj) = l2;
    *(f16*)(p + 4 * 65536 + oju) = h2;
    *(f16*)(p + 5 * 65536 + oju) = l2;
    *(f16*)(p + 6 * 65536 + ouj) = h1;
    *(f16*)(p + 7 * 65536 + ouj) = l1;
}

// ---- macros for the main kernel ----

// async-ish stage: load 2x16B (global, L2-resident) early; write to LDS late.
#define STAGE_LOAD(set, c) {                                              \
    const char* bp_ = (const char*)ws + (set) * 262144 + (c) * 2048;      \
    int o0_ = tid * 16, o1_ = o0_ + 4096;                                 \
    stg0 = *(const float4*)(bp_ + ((o0_ >> 11) * 65536) + (o0_ & 2047));  \
    stg1 = *(const float4*)(bp_ + ((o1_ >> 11) * 65536) + (o1_ & 2047)); }
#define STAGE_WRITE(bufw) {                                               \
    char* dp_ = (char*)&sSlice[bufw][0][0];                               \
    int o0_ = tid * 16;                                                   \
    *(float4*)(dp_ + o0_) = stg0;                                         \
    *(float4*)(dp_ + o0_ + 4096) = stg1; }

// B fragment: lane (n = s32) reads 8 consecutive-k f16 (16B) from slice sl.
#define LDB(dst, bufr, sl, ks) {                                          \
    int bo_ = s32 * 64 + (((((ks) << 1) | gh) ^ ((s32 >> 1) & 3)) << 4);  \
    dst = *(const f16x8*)((const char*)&sSlice[bufr][sl][0] + bo_); }

// A fragment from packed (hi|lo<<16) LDS tile rb[sample][jloc] stride 36.
#define LDA(a0, a1, ks) {                                                 \
    const u32* pw_ = rb + s32 * 36 + (ks) * 16 + gh * 8;                  \
    u32 w_[8];                                                            \
    *(uint4*)&w_[0] = *(const uint4*)pw_;                                 \
    *(uint4*)&w_[4] = *(const uint4*)(pw_ + 4);                           \
    union { u32 w[4]; f16x8 v; } uh_, ul_;                                \
    _Pragma("unroll")                                                     \
    for (int t_ = 0; t_ < 4; ++t_) {                                      \
        uh_.w[t_] = __builtin_amdgcn_perm(w_[2*t_+1], w_[2*t_], 0x05040100u); \
        ul_.w[t_] = __builtin_amdgcn_perm(w_[2*t_+1], w_[2*t_], 0x07060302u); \
    }                                                                     \
    a0 = uh_.v; a1 = ul_.v; }

// 3-term split product: Cm += A0B0 ; Cx += A0B1 + A1B0  (true = Cm + Cx/4096)
#define MFMA3(CM, CX, A0, A1, B0, B1) {                                   \
    CM = __builtin_amdgcn_mfma_f32_32x32x16_f16(A0, B0, CM, 0, 0, 0);     \
    CX = __builtin_amdgcn_mfma_f32_32x32x16_f16(A0, B1, CX, 0, 0, 0);     \
    CX = __builtin_amdgcn_mfma_f32_32x32x16_f16(A1, B0, CX, 0, 0, 0); }

// build A frag pair (hi, scaled-lo) from 8 f32
#define MKFRAG(a0, a1, src, base) {                                       \
    _Pragma("unroll")                                                     \
    for (int i_ = 0; i_ < 8; ++i_) {                                      \
        float v_ = (src)[(base) + i_];                                    \
        f16 h_ = (f16)v_;                                                 \
        (a0)[i_] = h_;                                                    \
        (a1)[i_] = (f16)((v_ - (float)h_) * 4096.0f);                     \
    } }

// C/D row for reg r: (r&3) + 8*(r>>2) + 4*(lane>>5)
#define SROW(r) (((r) & 3) + ((((r) >> 2)) << 3) + (gh << 2))

__global__ __launch_bounds__(TPB, 2)
void hopfield_mfma(const float* __restrict__ x,
                   const float* __restrict__ b1,
                   const float* __restrict__ b2,
                   const f16* __restrict__ ws,
                   float* __restrict__ out) {
    __shared__ __align__(16) f16 sSlice[2][4][1024];  // 16 KB, dbuf x 4 slices
    __shared__ float sB1[HID];                        // 4 KB
    __shared__ float sB2[UNITS];
    __shared__ __align__(16) u32 sR[WPB][32 * 36];    // 18 KB act tiles / f32 scratch
    __shared__ u16 sMsk[WPB][NCH * 64];               // 16 KB relu masks

    const int tid = threadIdx.x;
    const int wv = tid >> 6, ln = tid & 63;
    const int s32 = ln & 31, gh = ln >> 5;

    for (int i = tid; i < HID; i += TPB) sB1[i] = b1[i];
    if (tid < UNITS) sB2[tid] = b2[tid];

    u32* rb = &sR[wv][0];
    u16* mkb = &sMsk[wv][0];

    // lane owns sample s32 (of its wave's 32), u-slots: u = ks*16 + gh*8 + i
    const long samp = (long)blockIdx.x * SPB + wv * 32 + s32;
    float zb[16], acc[16], zcv[16];
    {
        const float* xr = x + samp * UNITS;
        #pragma unroll
        for (int ks = 0; ks < 2; ++ks) {
            float4 a = *(const float4*)(xr + ks * 16 + gh * 8);
            float4 b = *(const float4*)(xr + ks * 16 + gh * 8 + 4);
            zb[ks*8+0] = a.x; zb[ks*8+1] = a.y; zb[ks*8+2] = a.z; zb[ks*8+3] = a.w;
            zb[ks*8+4] = b.x; zb[ks*8+5] = b.y; zb[ks*8+6] = b.z; zb[ks*8+7] = b.w;
        }
    }
    #pragma unroll
    for (int i = 0; i < 16; ++i) zcv[i] = zb[i];

    float4 stg0, stg1;
    // prologue: stage fwd chunk 0 into buf 0
    STAGE_LOAD(0, 0)
    STAGE_WRITE(0)
    __syncthreads();

    #pragma unroll 1
    for (int step = 0; step < 10; ++step) {
        #pragma unroll
        for (int i = 0; i < 16; ++i) acc[i] = 0.f;

        #pragma unroll 1
        for (int sub = 0; sub < 4; ++sub) {
            f16x8 za0[2], za1[2];
            MKFRAG(za0[0], za1[0], zcv, 0)
            MKFRAG(za0[1], za1[1], zcv, 8)

            f32x16 ym, yx;
            #pragma unroll
            for (int r = 0; r < 16; ++r) { ym[r] = 0.f; yx[r] = 0.f; }

            // ================= forward: H = Zc@W1+b1, R=relu, Y += R@W2 =====
            #pragma unroll 1
            for (int c = 0; c < NCH; ++c) {
                int buf = c & 1;
                if (c < NCH - 1) { STAGE_LOAD(0, c + 1) } else { STAGE_LOAD(1, 0) }

                f32x16 hm, hx;
                #pragma unroll
                for (int r = 0; r < 16; ++r) { hm[r] = 0.f; hx[r] = 0.f; }
                #pragma unroll
                for (int ks = 0; ks < 2; ++ks) {
                    f16x8 b0, b1f;
                    LDB(b0, buf, 0, ks)
                    LDB(b1f, buf, 1, ks)
                    MFMA3(hm, hx, za0[ks], za1[ks], b0, b1f)
                }
                float bj = sB1[c * 32 + s32];   // col j = c*32 + (lane&31)
                u32 mb = 0;
                #pragma unroll
                for (int r = 0; r < 16; ++r) {
                    float h = hm[r] + hx[r] * (1.0f / 4096.0f) + bj;
                    if (h > 0.f) mb |= (1u << r);
                    float rv = fmaxf(h, 0.f);
                    f16 hh = (f16)rv;
                    f16 llo = (f16)((rv - (float)hh) * 4096.0f);
                    f16x2 pw = {hh, llo};
                    rb[SROW(r) * 36 + s32] = __builtin_bit_cast(u32, pw);
                }
                mkb[c * 64 + ln] = (u16)mb;
                #pragma unroll
                for (int ks = 0; ks < 2; ++ks) {
                    f16x8 a0, a1, b0, b1f;
                    LDA(a0, a1, ks)
                    LDB(b0, buf, 2, ks)
                    LDB(b1f, buf, 3, ks)
                    MFMA3(ym, yx, a0, a1, b0, b1f)
                }
                STAGE_WRITE(buf ^ 1)
                __syncthreads();
            }

            // ================= G = 8*(Y+b2)/||Y+b2|| =======================
            f16x8 ga0[2], ga1[2];
            {
                float bu = sB2[s32];            // col u = lane&31
                float yv[16];
                #pragma unroll
                for (int r = 0; r < 16; ++r) {
                    float yy = ym[r] + yx[r] * (1.0f / 4096.0f) + bu;
                    float t = yy * yy;
                    #pragma unroll
                    for (int m = 1; m < 32; m <<= 1) t += __shfl_xor(t, m, 64);
                    yv[r] = yy * (8.0f * rsqrtf(t));
                }
                float* fs = (float*)rb;
                #pragma unroll
                for (int r = 0; r < 16; ++r) fs[SROW(r) * 36 + s32] = yv[r];
                #pragma unroll
                for (int ks = 0; ks < 2; ++ks) {
                    const float* p = fs + s32 * 36 + ks * 16 + gh * 8;
                    float v8[8];
                    *(float4*)&v8[0] = *(const float4*)p;
                    *(float4*)&v8[4] = *(const float4*)(p + 4);
                    MKFRAG(ga0[ks], ga1[ks], v8, 0)
                }
            }

            // ================= backward: GR = G@W2T, M=mask*(-GR), K = M@W1T =
            f32x16 km, kx;
            #pragma unroll
            for (int r = 0; r < 16; ++r) { km[r] = 0.f; kx[r] = 0.f; }
            #pragma unroll 1
            for (int c = 0; c < NCH; ++c) {
                int buf = c & 1;
                if (c < NCH - 1) { STAGE_LOAD(1, c + 1) } else { STAGE_LOAD(0, 0) }

                f32x16 gm, gx;
                #pragma unroll
                for (int r = 0; r < 16; ++r) { gm[r] = 0.f; gx[r] = 0.f; }
                #pragma unroll
                for (int ks = 0; ks < 2; ++ks) {
                    f16x8 b0, b1f;
                    LDB(b0, buf, 0, ks)
                    LDB(b1f, buf, 1, ks)
                    MFMA3(gm, gx, ga0[ks], ga1[ks], b0, b1f)
                }
                u32 mb = mkb[c * 64 + ln];
                #pragma unroll
                for (int r = 0; r < 16; ++r) {
                    float gr = gm[r] + gx[r] * (1.0f / 4096.0f);
                    float mv = (mb & (1u << r)) ? -gr : 0.f;
                    f16 hh = (f16)mv;
                    f16 llo = (f16)((mv - (float)hh) * 4096.0f);
                    f16x2 pw = {hh, llo};
                    rb[SROW(r) * 36 + s32] = __builtin_bit_cast(u32, pw);
                }
                #pragma unroll
                for (int ks = 0; ks < 2; ++ks) {
                    f16x8 a0, a1, b0, b1f;
                    LDA(a0, a1, ks)
                    LDB(b0, buf, 2, ks)
                    LDB(b1f, buf, 3, ks)
                    MFMA3(km, kx, a0, a1, b0, b1f)
                }
                STAGE_WRITE(buf ^ 1)
                __syncthreads();
            }

            // ================= RK4 bookkeeping ==============================
            {
                float* fs = (float*)rb;
                #pragma unroll
                for (int r = 0; r < 16; ++r)
                    fs[SROW(r) * 36 + s32] = km[r] + kx[r] * (1.0f / 4096.0f);
                float aw = (sub == 0 || sub == 3) ? 1.f : 2.f;
                float cw = (sub == 2) ? 0.1f : 0.05f;
                #pragma unroll
                for (int ks = 0; ks < 2; ++ks) {
                    const float* p = fs + s32 * 36 + ks * 16 + gh * 8;
                    #pragma unroll
                    for (int i = 0; i < 8; ++i) {
                        float kv = p[i];
                        acc[ks*8+i] += aw * kv;
                        if (sub < 3) zcv[ks*8+i] = zb[ks*8+i] + cw * kv;
                    }
                }
            }
        } // sub

        #pragma unroll
        for (int i = 0; i < 16; ++i) {
            zb[i] += (0.1f / 6.0f) * acc[i];
            zcv[i] = zb[i];
        }
    } // step

    {
        float* orow = out + samp * UNITS;
        #pragma unroll
        for (int ks = 0; ks < 2; ++ks) {
            float4 a, b;
            a.x = zb[ks*8+0]; a.y = zb[ks*8+1]; a.z = zb[ks*8+2]; a.w = zb[ks*8+3];
            b.x = zb[ks*8+4]; b.y = zb[ks*8+5]; b.z = zb[ks*8+6]; b.w = zb[ks*8+7];
            *(float4*)(orow + ks * 16 + gh * 8) = a;
            *(float4*)(orow + ks * 16 + gh * 8 + 4) = b;
        }
    }
}

extern "C" void kernel_launch(void* const* d_in, const int* in_sizes, int n_in,
                              void* d_out, int out_size, void* d_ws, size_t ws_size,
                              hipStream_t stream) {
    const float* x  = (const float*)d_in[0];
    const float* W1 = (const float*)d_in[1];
    const float* b1 = (const float*)d_in[2];
    const float* W2 = (const float*)d_in[3];
    const float* b2 = (const float*)d_in[4];
    float* out = (float*)d_out;
    f16* ws = (f16*)d_ws;   // needs 512 KB
    hipLaunchKernelGGL(prep_weights, dim3(128), dim3(256), 0, stream, W1, W2, ws);
    hipLaunchKernelGGL(hopfield_mfma, dim3(NBLK), dim3(TPB), 0, stream,
                       x, b1, b2, ws, out);
}

// Round 8
// 5854.650 us; speedup vs baseline: 6.4814x; 1.0347x over previous
//
#include <hip/hip_runtime.h>

typedef _Float16 f16;
typedef __attribute__((ext_vector_type(8))) _Float16 f16x8;
typedef __attribute__((ext_vector_type(16))) float f32x16;
typedef __attribute__((ext_vector_type(2))) unsigned int u32x2;
typedef __attribute__((ext_vector_type(4))) unsigned int u32x4;
typedef unsigned int u32;
typedef unsigned short u16;

#define UNITS 32
#define HID   1024
#define NCH   32      // 32 chunks of 32 j
#define TPB   256     // 4 waves
#define WPB   4
#define SPB   128     // samples per block (4 waves x 32)
#define NBLK  1024
#define INV4096f (1.0f / 4096.0f)

static_assert(NBLK * SPB == 131072, "grid covers batch");

// Bank-swizzled byte offset of f16 (row, col) inside a 2KB [32][32] slice.
__device__ __forceinline__ int swz_off(int row, int col) {
    return row * 64 + ((((col >> 3) ^ ((row >> 1) & 3))) << 4) + ((col & 7) << 1);
}

// d_ws: 8 f16 arrays of 32768 elems (64KB each), each [32 chunks][2KB slice]:
// 0/1 W1jm hi/lo [c][jl][u]  (A of GEMM1': H^T = W1^T @ Z^T)
// 2/3 X2T  hi/lo [c][u][jl]  (A of GEMM2': Y^T = W2^T @ R^T)
// 4/5 W2n  hi/lo [c][jl][u]  (A of GEMM4': GR^T = W2 @ G^T)
// 6/7 X1N  hi/lo [c][u][jl]  (A of GEMM5': K^T = W1 @ M^T)
__global__ void prep_weights(const float* __restrict__ W1,
                             const float* __restrict__ W2,
                             f16* __restrict__ ws) {
    int idx = blockIdx.x * 256 + threadIdx.x;   // 0..32767
    int c = idx >> 10, rem = idx & 1023;
    int jl = rem >> 5, u = rem & 31;
    int j = c * 32 + jl;
    float w1 = W1[u * HID + j];
    f16 h1 = (f16)w1;
    f16 l1 = (f16)((w1 - (float)h1) * 4096.0f);
    float w2 = W2[j * UNITS + u];
    f16 h2 = (f16)w2;
    f16 l2 = (f16)((w2 - (float)h2) * 4096.0f);
    char* p = (char*)ws;
    int oju = c * 2048 + swz_off(jl, u);
    int ouj = c * 2048 + swz_off(u, jl);
    *(f16*)(p + 0 * 65536 + oju) = h1;
    *(f16*)(p + 1 * 65536 + oju) = l1;
    *(f16*)(p + 2 * 65536 + ouj) = h2;
    *(f16*)(p + 3 * 65536 + ouj) = l2;
    *(f16*)(p + 4 * 65536 + oju) = h2;
    *(f16*)(p + 5 * 65536 + oju) = l2;
    *(f16*)(p + 6 * 65536 + ouj) = h1;
    *(f16*)(p + 7 * 65536 + ouj) = l1;
}

__device__ __forceinline__ u32 pk2(f16 a, f16 b) {
    return ((u32)__builtin_bit_cast(u16, b) << 16) | (u32)__builtin_bit_cast(u16, a);
}
// v_permlane32_swap: r.x = {a.lanes0-31, b.lanes0-31}, r.y = {a.lanes32-63, b.lanes32-63}
__device__ __forceinline__ void plswap(u32& a, u32& b) {
    u32x2 r = __builtin_amdgcn_permlane32_swap(a, b, false, false);
    a = r.x; b = r.y;
}

// ---- staging (T14 issue-early / write-late), same as round-7 ----
#define STAGE_LOAD(set, c) {                                              \
    const char* bp_ = (const char*)ws + (set) * 262144 + (c) * 2048;      \
    int o0_ = tid * 16, o1_ = o0_ + 4096;                                 \
    stg0 = *(const float4*)(bp_ + ((o0_ >> 11) * 65536) + (o0_ & 2047));  \
    stg1 = *(const float4*)(bp_ + ((o1_ >> 11) * 65536) + (o1_ & 2047)); }
#define STAGE_WRITE(bufw) {                                               \
    char* dp_ = (char*)&sSlice[bufw][0][0];                               \
    int o0_ = tid * 16;                                                   \
    *(float4*)(dp_ + o0_) = stg0;                                         \
    *(float4*)(dp_ + o0_ + 4096) = stg1; }

// A fragment (row = lane&31, k = (lane>>5)*8+i): lane reads 16B from slice sl.
#define LDB(dst, bufr, sl, ks) {                                          \
    int bo_ = s32 * 64 + (((((ks) << 1) | gh) ^ ((s32 >> 1) & 3)) << 4);  \
    dst = *(const f16x8*)((const char*)&sSlice[bufr][sl][0] + bo_); }

// vals[r] (own sample, j/u = SROW(r)) -> B-frags (k-contig), hi + scaled-lo,
// via 8 permlane32_swap. F0: k=0..15, F1: k=16..31.
#define BUILD_FRAGS(F0, F1, L0, L1, V) {                                  \
    u32 owh[8], owl[8];                                                   \
    _Pragma("unroll")                                                     \
    for (int q_ = 0; q_ < 4; ++q_) {                                      \
        _Pragma("unroll")                                                 \
        for (int w_ = 0; w_ < 2; ++w_) {                                  \
            float v0_ = (V)[4*q_ + 2*w_], v1_ = (V)[4*q_ + 2*w_ + 1];     \
            f16 h0_ = (f16)v0_, h1_ = (f16)v1_;                           \
            owh[2*q_ + w_] = pk2(h0_, h1_);                               \
            f16 l0_ = (f16)((v0_ - (float)h0_) * 4096.0f);                \
            f16 l1_ = (f16)((v1_ - (float)h1_) * 4096.0f);                \
            owl[2*q_ + w_] = pk2(l0_, l1_);                               \
        }                                                                 \
    }                                                                     \
    {                                                                     \
        u32 a0_ = owh[0], b0_ = owh[2]; plswap(a0_, b0_);                 \
        u32 a1_ = owh[1], b1_ = owh[3]; plswap(a1_, b1_);                 \
        F0 = __builtin_bit_cast(f16x8, (u32x4){a0_, a1_, b0_, b1_});      \
        u32 c0_ = owh[4], d0_ = owh[6]; plswap(c0_, d0_);                 \
        u32 c1_ = owh[5], d1_ = owh[7]; plswap(c1_, d1_);                 \
        F1 = __builtin_bit_cast(f16x8, (u32x4){c0_, c1_, d0_, d1_});      \
        u32 e0_ = owl[0], f0_ = owl[2]; plswap(e0_, f0_);                 \
        u32 e1_ = owl[1], f1_ = owl[3]; plswap(e1_, f1_);                 \
        L0 = __builtin_bit_cast(f16x8, (u32x4){e0_, e1_, f0_, f1_});      \
        u32 g0_ = owl[4], h0_ = owl[6]; plswap(g0_, h0_);                 \
        u32 g1_ = owl[5], h1_ = owl[7]; plswap(g1_, h1_);                 \
        L1 = __builtin_bit_cast(f16x8, (u32x4){g0_, g1_, h0_, h1_});      \
    } }

#define MFMA(d, a, b, c) d = __builtin_amdgcn_mfma_f32_32x32x16_f16(a, b, c, 0, 0, 0)

__global__ __launch_bounds__(TPB, 4)
void hopfield_mfma2(const float* __restrict__ x,
                    const float* __restrict__ b1,
                    const float* __restrict__ b2,
                    const f16* __restrict__ ws,
                    float* __restrict__ out) {
    __shared__ __align__(16) f16 sSlice[2][4][1024];  // 16 KB dbuf
    __shared__ __align__(16) float sB1p[HID];         // 4 KB, [c][gh][r] permuted
    __shared__ __align__(16) float sB2p[UNITS];       // [gh][r] permuted
    __shared__ u16 sMsk[WPB][NCH * 64];               // 16 KB relu masks

    const int tid = threadIdx.x;
    const int wv = tid >> 6, ln = tid & 63;
    const int s32 = ln & 31, gh = ln >> 5;

    // biases pre-permuted into C-row (SROW) order: SROW(r) = (r&3)+8*(r>>2)+4*gh
    for (int i = tid; i < HID; i += TPB) {
        int c = i >> 5, g_ = (i >> 4) & 1, r = i & 15;
        sB1p[i] = b1[c * 32 + ((r & 3) + ((r >> 2) << 3) + (g_ << 2))];
    }
    if (tid < UNITS) {
        int g_ = (tid >> 4) & 1, r = tid & 15;
        sB2p[tid] = b2[(r & 3) + ((r >> 2) << 3) + (g_ << 2)];
    }

    u16* mkb = &sMsk[wv][0];

    // lane pair (s32, s32+32) jointly owns sample; this lane holds u=SROW(r)
    const long samp = (long)blockIdx.x * SPB + wv * 32 + s32;
    float zb[16], acc[16], zcv[16];
    {
        const float* xr = x + samp * UNITS;
        #pragma unroll
        for (int q = 0; q < 4; ++q) {
            float4 v = *(const float4*)(xr + 8 * q + 4 * gh);
            zb[4*q+0] = v.x; zb[4*q+1] = v.y; zb[4*q+2] = v.z; zb[4*q+3] = v.w;
        }
    }

    float4 stg0, stg1;
    STAGE_LOAD(0, 0)
    STAGE_WRITE(0)
    __syncthreads();

    #pragma unroll 1
    for (int step = 0; step < 10; ++step) {
        #pragma unroll
        for (int r = 0; r < 16; ++r) { acc[r] = 0.f; zcv[r] = zb[r]; }

        #pragma unroll 1
        for (int sub = 0; sub < 4; ++sub) {
            f16x8 za0h, za1h, za0l, za1l;
            BUILD_FRAGS(za0h, za1h, za0l, za1l, zcv)

            f32x16 ym, yx;
            {   // init Y^T accumulator with b2 (C-row order)
                const float4* bp = (const float4*)(sB2p + gh * 16);
                float4 v0 = bp[0], v1 = bp[1], v2 = bp[2], v3 = bp[3];
                ym[0]=v0.x; ym[1]=v0.y; ym[2]=v0.z; ym[3]=v0.w;
                ym[4]=v1.x; ym[5]=v1.y; ym[6]=v1.z; ym[7]=v1.w;
                ym[8]=v2.x; ym[9]=v2.y; ym[10]=v2.z; ym[11]=v2.w;
                ym[12]=v3.x; ym[13]=v3.y; ym[14]=v3.z; ym[15]=v3.w;
            }
            #pragma unroll
            for (int r = 0; r < 16; ++r) yx[r] = 0.f;

            // ============ forward: H^T = W1^T@Z^T (+b1), R^T, Y^T += W2^T@R^T
            #pragma unroll 1
            for (int c = 0; c < NCH; ++c) {
                int buf = c & 1;
                if (c < NCH - 1) { STAGE_LOAD(0, c + 1) } else { STAGE_LOAD(1, 0) }

                f32x16 hm, hx;
                {   // C-init with b1 (bias folded into MFMA accumulate)
                    const float4* bp = (const float4*)(sB1p + c * 32 + gh * 16);
                    float4 v0 = bp[0], v1 = bp[1], v2 = bp[2], v3 = bp[3];
                    hm[0]=v0.x; hm[1]=v0.y; hm[2]=v0.z; hm[3]=v0.w;
                    hm[4]=v1.x; hm[5]=v1.y; hm[6]=v1.z; hm[7]=v1.w;
                    hm[8]=v2.x; hm[9]=v2.y; hm[10]=v2.z; hm[11]=v2.w;
                    hm[12]=v3.x; hm[13]=v3.y; hm[14]=v3.z; hm[15]=v3.w;
                }
                #pragma unroll
                for (int r = 0; r < 16; ++r) hx[r] = 0.f;

                f16x8 wh, wl;
                LDB(wh, buf, 0, 0) LDB(wl, buf, 1, 0)
                MFMA(hm, wh, za0h, hm); MFMA(hx, wh, za0l, hx); MFMA(hx, wl, za0h, hx);
                LDB(wh, buf, 0, 1) LDB(wl, buf, 1, 1)
                MFMA(hm, wh, za1h, hm); MFMA(hx, wh, za1l, hx); MFMA(hx, wl, za1h, hx);

                float rv[16]; u32 mb = 0;
                #pragma unroll
                for (int r = 0; r < 16; ++r) {
                    float h = fmaf(hx[r], INV4096f, hm[r]);
                    mb |= (h > 0.f) ? (1u << r) : 0u;
                    rv[r] = fmaxf(h, 0.f);
                }
                mkb[c * 64 + ln] = (u16)mb;

                f16x8 rf0, rf1, rl0, rl1;
                BUILD_FRAGS(rf0, rf1, rl0, rl1, rv)
                LDB(wh, buf, 2, 0) LDB(wl, buf, 3, 0)
                MFMA(ym, wh, rf0, ym); MFMA(yx, wh, rl0, yx); MFMA(yx, wl, rf0, yx);
                LDB(wh, buf, 2, 1) LDB(wl, buf, 3, 1)
                MFMA(ym, wh, rf1, ym); MFMA(yx, wh, rl1, yx); MFMA(yx, wl, rf1, yx);

                STAGE_WRITE(buf ^ 1)
                __syncthreads();
            }

            // ============ G = 8*(Y)/||Y|| — register-local + one cross-half add
            f16x8 gf0, gf1, gl0, gl1;
            {
                float yv[16], t = 0.f;
                #pragma unroll
                for (int r = 0; r < 16; ++r) {
                    float y = fmaf(yx[r], INV4096f, ym[r]);
                    yv[r] = y;
                    t = fmaf(y, y, t);
                }
                t += __shfl_xor(t, 32, 64);
                float s8 = 8.0f * rsqrtf(t);
                #pragma unroll
                for (int r = 0; r < 16; ++r) yv[r] *= s8;
                BUILD_FRAGS(gf0, gf1, gl0, gl1, yv)
            }

            // ============ backward: GR^T = W2@G^T, M = -mask*GR, K^T += W1@M^T
            f32x16 km, kx;
            #pragma unroll
            for (int r = 0; r < 16; ++r) { km[r] = 0.f; kx[r] = 0.f; }

            #pragma unroll 1
            for (int c = 0; c < NCH; ++c) {
                int buf = c & 1;
                if (c < NCH - 1) { STAGE_LOAD(1, c + 1) } else { STAGE_LOAD(0, 0) }

                f32x16 gm, gx;
                #pragma unroll
                for (int r = 0; r < 16; ++r) { gm[r] = 0.f; gx[r] = 0.f; }

                f16x8 wh, wl;
                LDB(wh, buf, 0, 0) LDB(wl, buf, 1, 0)
                MFMA(gm, wh, gf0, gm); MFMA(gx, wh, gl0, gx); MFMA(gx, wl, gf0, gx);
                LDB(wh, buf, 0, 1) LDB(wl, buf, 1, 1)
                MFMA(gm, wh, gf1, gm); MFMA(gx, wh, gl1, gx); MFMA(gx, wl, gf1, gx);

                u32 mb = mkb[c * 64 + ln];
                float mv[16];
                #pragma unroll
                for (int r = 0; r < 16; ++r) {
                    float gr = fmaf(gx[r], INV4096f, gm[r]);
                    mv[r] = (mb & (1u << r)) ? -gr : 0.f;
                }

                f16x8 mf0, mf1, ml0, ml1;
                BUILD_FRAGS(mf0, mf1, ml0, ml1, mv)
                LDB(wh, buf, 2, 0) LDB(wl, buf, 3, 0)
                MFMA(km, wh, mf0, km); MFMA(kx, wh, ml0, kx); MFMA(kx, wl, mf0, kx);
                LDB(wh, buf, 2, 1) LDB(wl, buf, 3, 1)
                MFMA(km, wh, mf1, km); MFMA(kx, wh, ml1, kx); MFMA(kx, wl, mf1, kx);

                STAGE_WRITE(buf ^ 1)
                __syncthreads();
            }

            // ============ RK4 bookkeeping — fully register-local
            {
                float aw = (sub == 0 || sub == 3) ? 1.f : 2.f;
                float cw = (sub == 2) ? 0.1f : 0.05f;
                #pragma unroll
                for (int r = 0; r < 16; ++r) {
                    float kv = fmaf(kx[r], INV4096f, km[r]);
                    acc[r] += aw * kv;
                    if (sub < 3) zcv[r] = fmaf(cw, kv, zb[r]);
                }
            }
        } // sub

        #pragma unroll
        for (int r = 0; r < 16; ++r) zb[r] = fmaf(0.1f / 6.0f, acc[r], zb[r]);
    } // step

    {
        float* orow = out + samp * UNITS;
        #pragma unroll
        for (int q = 0; q < 4; ++q) {
            float4 v;
            v.x = zb[4*q+0]; v.y = zb[4*q+1]; v.z = zb[4*q+2]; v.w = zb[4*q+3];
            *(float4*)(orow + 8 * q + 4 * gh) = v;
        }
    }
}

extern "C" void kernel_launch(void* const* d_in, const int* in_sizes, int n_in,
                              void* d_out, int out_size, void* d_ws, size_t ws_size,
                              hipStream_t stream) {
    const float* x  = (const float*)d_in[0];
    const float* W1 = (const float*)d_in[1];
    const float* b1 = (const float*)d_in[2];
    const float* W2 = (const float*)d_in[3];
    const float* b2 = (const float*)d_in[4];
    float* out = (float*)d_out;
    f16* ws = (f16*)d_ws;   // 512 KB
    hipLaunchKernelGGL(prep_weights, dim3(128), dim3(256), 0, stream, W1, W2, ws);
    hipLaunchKernelGGL(hopfield_mfma2, dim3(NBLK), dim3(TPB), 0, stream,
                       x, b1, b2, ws, out);
}

// Round 10
// 4772.713 us; speedup vs baseline: 7.9507x; 1.2267x over previous
//
#include <hip/hip_runtime.h>

typedef _Float16 f16;
typedef __attribute__((ext_vector_type(8))) _Float16 f16x8;
typedef __attribute__((ext_vector_type(16))) float f32x16;
typedef __attribute__((ext_vector_type(2))) unsigned int u32x2;
typedef __attribute__((ext_vector_type(4))) unsigned int u32x4;
typedef unsigned int u32;
typedef unsigned short u16;

#define UNITS 32
#define HID   1024
#define NCH   32      // 32 chunks of 32 j
#define TPB   256     // 4 waves
#define WPB   4
#define SPB   128     // samples per block (4 waves x 32)
#define NBLK  1024
#define INV4096f (1.0f / 4096.0f)

static_assert(NBLK * SPB == 131072, "grid covers batch");

// Bank-swizzled byte offset of f16 (row, col) inside a 2KB [32][32] slice.
__device__ __forceinline__ int swz_off(int row, int col) {
    return row * 64 + ((((col >> 3) ^ ((row >> 1) & 3))) << 4) + ((col & 7) << 1);
}

// d_ws: 8 f16 arrays of 32768 elems (64KB each), each [32 chunks][2KB slice]:
// 0/1 W1jm hi/lo [c][jl][u]  (A of GEMM1': H^T = W1^T @ Z^T)
// 2/3 X2T  hi/lo [c][u][jl]  (A of GEMM2': Y^T = W2^T @ R^T)
// 4/5 W2n  hi/lo [c][jl][u]  (A of GEMM4': GR^T = W2 @ G^T)
// 6/7 X1N  hi/lo [c][u][jl]  (A of GEMM5': K^T = W1 @ M^T)
__global__ void prep_weights(const float* __restrict__ W1,
                             const float* __restrict__ W2,
                             f16* __restrict__ ws) {
    int idx = blockIdx.x * 256 + threadIdx.x;   // 0..32767
    int c = idx >> 10, rem = idx & 1023;
    int jl = rem >> 5, u = rem & 31;
    int j = c * 32 + jl;
    float w1 = W1[u * HID + j];
    f16 h1 = (f16)w1;
    f16 l1 = (f16)((w1 - (float)h1) * 4096.0f);
    float w2 = W2[j * UNITS + u];
    f16 h2 = (f16)w2;
    f16 l2 = (f16)((w2 - (float)h2) * 4096.0f);
    char* p = (char*)ws;
    int oju = c * 2048 + swz_off(jl, u);
    int ouj = c * 2048 + swz_off(u, jl);
    *(f16*)(p + 0 * 65536 + oju) = h1;
    *(f16*)(p + 1 * 65536 + oju) = l1;
    *(f16*)(p + 2 * 65536 + ouj) = h2;
    *(f16*)(p + 3 * 65536 + ouj) = l2;
    *(f16*)(p + 4 * 65536 + oju) = h2;
    *(f16*)(p + 5 * 65536 + oju) = l2;
    *(f16*)(p + 6 * 65536 + ouj) = h1;
    *(f16*)(p + 7 * 65536 + ouj) = l1;
}

// v_permlane32_swap: r.x = {a.lanes0-31, b.lanes0-31}, r.y = {a.lanes32-63, b.lanes32-63}
__device__ __forceinline__ void plswap(u32& a, u32& b) {
    u32x2 r = __builtin_amdgcn_permlane32_swap(a, b, false, false);
    a = r.x; b = r.y;
}

// ---- staging (T14 issue-early / write-late) ----
#define STAGE_LOAD(set, c) {                                              \
    const char* bp_ = (const char*)ws + (set) * 262144 + (c) * 2048;      \
    int o0_ = tid * 16, o1_ = o0_ + 4096;                                 \
    stg0 = *(const float4*)(bp_ + ((o0_ >> 11) * 65536) + (o0_ & 2047));  \
    stg1 = *(const float4*)(bp_ + ((o1_ >> 11) * 65536) + (o1_ & 2047)); }
#define STAGE_WRITE(bufw) {                                               \
    char* dp_ = (char*)&sSlice[bufw][0][0];                               \
    int o0_ = tid * 16;                                                   \
    *(float4*)(dp_ + o0_) = stg0;                                         \
    *(float4*)(dp_ + o0_ + 4096) = stg1; }

// A fragment (row = lane&31, k = (lane>>5)*8+i): lane reads 16B from slice sl.
#define LDB(dst, bufr, sl, ks) {                                          \
    int bo_ = s32 * 64 + (((((ks) << 1) | gh) ^ ((s32 >> 1) & 3)) << 4);  \
    dst = *(const f16x8*)((const char*)&sSlice[bufr][sl][0] + bo_); }

// vals[r] (own sample, j/u = SROW(r)) -> B-frags (k-contig), hi + scaled-lo,
// packed-RTZ converts (1 op/pair) + 8 permlane32_swap. F0: k=0..15, F1: 16..31.
#define BUILD_FRAGS(F0, F1, L0, L1, V) {                                  \
    u32 owh[8], owl[8];                                                   \
    _Pragma("unroll")                                                     \
    for (int i_ = 0; i_ < 8; ++i_) {                                      \
        float v0_ = (V)[2*i_], v1_ = (V)[2*i_ + 1];                       \
        auto hp_ = __builtin_amdgcn_cvt_pkrtz(v0_, v1_);                  \
        owh[i_] = __builtin_bit_cast(u32, hp_);                           \
        float r0_ = (v0_ - (float)hp_[0]) * 4096.0f;                      \
        float r1_ = (v1_ - (float)hp_[1]) * 4096.0f;                      \
        auto lp_ = __builtin_amdgcn_cvt_pkrtz(r0_, r1_);                  \
        owl[i_] = __builtin_bit_cast(u32, lp_);                           \
    }                                                                     \
    {                                                                     \
        u32 a0_ = owh[0], b0_ = owh[2]; plswap(a0_, b0_);                 \
        u32 a1_ = owh[1], b1_ = owh[3]; plswap(a1_, b1_);                 \
        F0 = __builtin_bit_cast(f16x8, (u32x4){a0_, a1_, b0_, b1_});      \
        u32 c0_ = owh[4], d0_ = owh[6]; plswap(c0_, d0_);                 \
        u32 c1_ = owh[5], d1_ = owh[7]; plswap(c1_, d1_);                 \
        F1 = __builtin_bit_cast(f16x8, (u32x4){c0_, c1_, d0_, d1_});      \
        u32 e0_ = owl[0], f0_ = owl[2]; plswap(e0_, f0_);                 \
        u32 e1_ = owl[1], f1_ = owl[3]; plswap(e1_, f1_);                 \
        L0 = __builtin_bit_cast(f16x8, (u32x4){e0_, e1_, f0_, f1_});      \
        u32 g0_ = owl[4], h0_ = owl[6]; plswap(g0_, h0_);                 \
        u32 g1_ = owl[5], h1_ = owl[7]; plswap(g1_, h1_);                 \
        L1 = __builtin_bit_cast(f16x8, (u32x4){g0_, g1_, h0_, h1_});      \
    } }

#define MFMA(d, a, b, c) d = __builtin_amdgcn_mfma_f32_32x32x16_f16(a, b, c, 0, 0, 0)

__global__ __launch_bounds__(TPB, 2)
void hopfield_mfma2(const float* __restrict__ x,
                    const float* __restrict__ b1,
                    const float* __restrict__ b2,
                    const f16* __restrict__ ws,
                    float* __restrict__ out) {
    __shared__ __align__(16) f16 sSlice[2][4][1024];  // 16 KB dbuf
    __shared__ __align__(16) float sB1p[HID];         // 4 KB, [c][gh][r] permuted
    __shared__ __align__(16) float sB2p[UNITS];       // [gh][r] permuted
    __shared__ u16 sMsk[WPB][NCH * 64];               // 16 KB relu masks

    const int tid = threadIdx.x;
    const int wv = tid >> 6, ln = tid & 63;
    const int s32 = ln & 31, gh = ln >> 5;

    // biases pre-permuted into C-row (SROW) order: SROW(r) = (r&3)+8*(r>>2)+4*gh
    for (int i = tid; i < HID; i += TPB) {
        int c = i >> 5, g_ = (i >> 4) & 1, r = i & 15;
        sB1p[i] = b1[c * 32 + ((r & 3) + ((r >> 2) << 3) + (g_ << 2))];
    }
    if (tid < UNITS) {
        int g_ = (tid >> 4) & 1, r = tid & 15;
        sB2p[tid] = b2[(r & 3) + ((r >> 2) << 3) + (g_ << 2)];
    }

    u16* mkb = &sMsk[wv][0];

    // lane pair (s32, s32+32) jointly owns sample; this lane holds u=SROW(r)
    const long samp = (long)blockIdx.x * SPB + wv * 32 + s32;
    float zb[16], acc[16], zcv[16];
    {
        const float* xr = x + samp * UNITS;
        #pragma unroll
        for (int q = 0; q < 4; ++q) {
            float4 v = *(const float4*)(xr + 8 * q + 4 * gh);
            zb[4*q+0] = v.x; zb[4*q+1] = v.y; zb[4*q+2] = v.z; zb[4*q+3] = v.w;
        }
    }

    float4 stg0, stg1;
    STAGE_LOAD(0, 0)
    STAGE_WRITE(0)
    __syncthreads();

    #pragma unroll 1
    for (int step = 0; step < 10; ++step) {
        #pragma unroll
        for (int r = 0; r < 16; ++r) { acc[r] = 0.f; zcv[r] = zb[r]; }

        #pragma unroll 1
        for (int sub = 0; sub < 4; ++sub) {
            f16x8 za0h, za1h, za0l, za1l;
            BUILD_FRAGS(za0h, za1h, za0l, za1l, zcv)

            f32x16 ym, yx;
            {   // init Y^T accumulator with b2 (C-row order)
                const float4* bp = (const float4*)(sB2p + gh * 16);
                float4 v0 = bp[0], v1 = bp[1], v2 = bp[2], v3 = bp[3];
                ym[0]=v0.x; ym[1]=v0.y; ym[2]=v0.z; ym[3]=v0.w;
                ym[4]=v1.x; ym[5]=v1.y; ym[6]=v1.z; ym[7]=v1.w;
                ym[8]=v2.x; ym[9]=v2.y; ym[10]=v2.z; ym[11]=v2.w;
                ym[12]=v3.x; ym[13]=v3.y; ym[14]=v3.z; ym[15]=v3.w;
            }
            #pragma unroll
            for (int r = 0; r < 16; ++r) yx[r] = 0.f;

            // ============ forward: H^T = W1^T@Z^T (+b1), R^T, Y^T += W2^T@R^T
            #pragma unroll 1
            for (int c = 0; c < NCH; ++c) {
                int buf = c & 1;
                if (c < NCH - 1) { STAGE_LOAD(0, c + 1) } else { STAGE_LOAD(1, 0) }

                f32x16 hm, hx;
                {   // C-init with b1 (bias folded into MFMA accumulate)
                    const float4* bp = (const float4*)(sB1p + c * 32 + gh * 16);
                    float4 v0 = bp[0], v1 = bp[1], v2 = bp[2], v3 = bp[3];
                    hm[0]=v0.x; hm[1]=v0.y; hm[2]=v0.z; hm[3]=v0.w;
                    hm[4]=v1.x; hm[5]=v1.y; hm[6]=v1.z; hm[7]=v1.w;
                    hm[8]=v2.x; hm[9]=v2.y; hm[10]=v2.z; hm[11]=v2.w;
                    hm[12]=v3.x; hm[13]=v3.y; hm[14]=v3.z; hm[15]=v3.w;
                }
                #pragma unroll
                for (int r = 0; r < 16; ++r) hx[r] = 0.f;

                f16x8 wh, wl;
                LDB(wh, buf, 0, 0) LDB(wl, buf, 1, 0)
                MFMA(hm, wh, za0h, hm); MFMA(hx, wh, za0l, hx); MFMA(hx, wl, za0h, hx);
                LDB(wh, buf, 0, 1) LDB(wl, buf, 1, 1)
                MFMA(hm, wh, za1h, hm); MFMA(hx, wh, za1l, hx); MFMA(hx, wl, za1h, hx);

                float rv[16]; u32 mb = 0;
                #pragma unroll
                for (int r = 0; r < 16; ++r) {
                    float h = fmaf(hx[r], INV4096f, hm[r]);
                    mb |= (h > 0.f) ? (1u << r) : 0u;
                    rv[r] = fmaxf(h, 0.f);
                }
                mkb[c * 64 + ln] = (u16)mb;

                f16x8 rf0, rf1, rl0, rl1;
                BUILD_FRAGS(rf0, rf1, rl0, rl1, rv)
                LDB(wh, buf, 2, 0) LDB(wl, buf, 3, 0)
                MFMA(ym, wh, rf0, ym); MFMA(yx, wh, rl0, yx); MFMA(yx, wl, rf0, yx);
                LDB(wh, buf, 2, 1) LDB(wl, buf, 3, 1)
                MFMA(ym, wh, rf1, ym); MFMA(yx, wh, rl1, yx); MFMA(yx, wl, rf1, yx);

                STAGE_WRITE(buf ^ 1)
                __syncthreads();
            }

            // ============ G = 8*(Y)/||Y|| — register-local + one cross-half add
            f16x8 gf0, gf1, gl0, gl1;
            {
                float yv[16], t = 0.f;
                #pragma unroll
                for (int r = 0; r < 16; ++r) {
                    float y = fmaf(yx[r], INV4096f, ym[r]);
                    yv[r] = y;
                    t = fmaf(y, y, t);
                }
                t += __shfl_xor(t, 32, 64);
                float s8 = 8.0f * rsqrtf(t);
                #pragma unroll
                for (int r = 0; r < 16; ++r) yv[r] *= s8;
                BUILD_FRAGS(gf0, gf1, gl0, gl1, yv)
            }

            // ============ backward: GR^T = W2@G^T, M = -mask*GR, K^T += W1@M^T
            f32x16 km, kx;
            #pragma unroll
            for (int r = 0; r < 16; ++r) { km[r] = 0.f; kx[r] = 0.f; }

            #pragma unroll 1
            for (int c = 0; c < NCH; ++c) {
                int buf = c & 1;
                if (c < NCH - 1) { STAGE_LOAD(1, c + 1) } else { STAGE_LOAD(0, 0) }

                f32x16 gm, gx;
                #pragma unroll
                for (int r = 0; r < 16; ++r) { gm[r] = 0.f; gx[r] = 0.f; }

                f16x8 wh, wl;
                LDB(wh, buf, 0, 0) LDB(wl, buf, 1, 0)
                MFMA(gm, wh, gf0, gm); MFMA(gx, wh, gl0, gx); MFMA(gx, wl, gf0, gx);
                LDB(wh, buf, 0, 1) LDB(wl, buf, 1, 1)
                MFMA(gm, wh, gf1, gm); MFMA(gx, wh, gl1, gx); MFMA(gx, wl, gf1, gx);

                u32 mb = mkb[c * 64 + ln];
                float mv[16];
                #pragma unroll
                for (int r = 0; r < 16; ++r) {
                    float gr = fmaf(gx[r], INV4096f, gm[r]);
                    mv[r] = (mb & (1u << r)) ? -gr : 0.f;
                }

                f16x8 mf0, mf1, ml0, ml1;
                BUILD_FRAGS(mf0, mf1, ml0, ml1, mv)
                LDB(wh, buf, 2, 0) LDB(wl, buf, 3, 0)
                MFMA(km, wh, mf0, km); MFMA(kx, wh, ml0, kx); MFMA(kx, wl, mf0, kx);
                LDB(wh, buf, 2, 1) LDB(wl, buf, 3, 1)
                MFMA(km, wh, mf1, km); MFMA(kx, wh, ml1, kx); MFMA(kx, wl, mf1, kx);

                STAGE_WRITE(buf ^ 1)
                __syncthreads();
            }

            // ============ RK4 bookkeeping — fully register-local
            {
                float aw = (sub == 0 || sub == 3) ? 1.f : 2.f;
                float cw = (sub == 2) ? 0.1f : 0.05f;
                #pragma unroll
                for (int r = 0; r < 16; ++r) {
                    float kv = fmaf(kx[r], INV4096f, km[r]);
                    acc[r] += aw * kv;
                    if (sub < 3) zcv[r] = fmaf(cw, kv, zb[r]);
                }
            }
        } // sub

        #pragma unroll
        for (int r = 0; r < 16; ++r) zb[r] = fmaf(0.1f / 6.0f, acc[r], zb[r]);
    } // step

    {
        float* orow = out + samp * UNITS;
        #pragma unroll
        for (int q = 0; q < 4; ++q) {
            float4 v;
            v.x = zb[4*q+0]; v.y = zb[4*q+1]; v.z = zb[4*q+2]; v.w = zb[4*q+3];
            *(float4*)(orow + 8 * q + 4 * gh) = v;
        }
    }
}

extern "C" void kernel_launch(void* const* d_in, const int* in_sizes, int n_in,
                              void* d_out, int out_size, void* d_ws, size_t ws_size,
                              hipStream_t stream) {
    const float* x  = (const float*)d_in[0];
    const float* W1 = (const float*)d_in[1];
    const float* b1 = (const float*)d_in[2];
    const float* W2 = (const float*)d_in[3];
    const float* b2 = (const float*)d_in[4];
    float* out = (float*)d_out;
    f16* ws = (f16*)d_ws;   // 512 KB
    hipLaunchKernelGGL(prep_weights, dim3(128), dim3(256), 0, stream, W1, W2, ws);
    hipLaunchKernelGGL(hopfield_mfma2, dim3(NBLK), dim3(TPB), 0, stream,
                       x, b1, b2, ws, out);
}

// Round 11
// 4714.417 us; speedup vs baseline: 8.0490x; 1.0124x over previous
//
#include <hip/hip_runtime.h>

typedef _Float16 f16;
typedef __attribute__((ext_vector_type(8))) _Float16 f16x8;
typedef __attribute__((ext_vector_type(16))) float f32x16;
typedef __attribute__((ext_vector_type(2))) unsigned int u32x2;
typedef __attribute__((ext_vector_type(4))) unsigned int u32x4;
typedef unsigned int u32;
typedef unsigned short u16;

#define UNITS 32
#define HID   1024
#define NCH   32      // 32 chunks of 32 j
#define TPB   256     // 4 waves
#define WPB   4
#define SPB   128     // samples per block
#define NBLK  1024
#define BWDOFF 262144

static_assert(NBLK * SPB == 131072, "grid covers batch");

// d_ws (512 KB): two regions (FWD @0, BWD @256KB), each
// [c:32][load:8][lane:64][16B], load = slice*2 + ks.
// FWD slices: 0/1 = W1^T hi/lo (A of H^T=W1^T@Z^T), 2/3 = W2^T hi/lo (A of Y^T)
// BWD slices: 0/1 = W2  hi/lo (A of GR^T=W2@G^T),   2/3 = W1  hi/lo (A of K^T)
// Fragment element (row, k): lane = row + 32*((k>>3)&1), ks = k>>4, byte = (k&7)*2.
// lo residuals are UNSCALED: lo = f16(v - hi); all 3 split MFMAs share one C.
__global__ void prep_weights(const float* __restrict__ W1,
                             const float* __restrict__ W2,
                             f16* __restrict__ ws) {
    int idx = blockIdx.x * 256 + threadIdx.x;   // (c, jl, u)
    int c = idx >> 10, rem = idx & 1023;
    int jl = rem >> 5, u = rem & 31;
    int j = c * 32 + jl;
    float w1 = W1[u * HID + j];
    f16 h1 = (f16)w1;
    f16 l1 = (f16)(w1 - (float)h1);
    float w2 = W2[j * UNITS + u];
    f16 h2 = (f16)w2;
    f16 l2 = (f16)(w2 - (float)h2);
    char* p = (char*)ws;
    auto off = [&](int region, int slice, int row, int k) {
        int ks = k >> 4;
        int lane = row + ((k >> 3) & 1) * 32;
        return region + c * 8192 + (slice * 2 + ks) * 1024 + lane * 16 + (k & 7) * 2;
    };
    *(f16*)(p + off(0, 0, jl, u))      = h1;
    *(f16*)(p + off(0, 1, jl, u))      = l1;
    *(f16*)(p + off(0, 2, u, jl))      = h2;
    *(f16*)(p + off(0, 3, u, jl))      = l2;
    *(f16*)(p + off(BWDOFF, 0, jl, u)) = h2;
    *(f16*)(p + off(BWDOFF, 1, jl, u)) = l2;
    *(f16*)(p + off(BWDOFF, 2, u, jl)) = h1;
    *(f16*)(p + off(BWDOFF, 3, u, jl)) = l1;
}

// v_permlane32_swap: r.x = {a.lo32lanes, b.lo32lanes}, r.y = {a.hi, b.hi}
__device__ __forceinline__ void plswap(u32& a, u32& b) {
    u32x2 r = __builtin_amdgcn_permlane32_swap(a, b, false, false);
    a = r.x; b = r.y;
}

// 8 direct global 16B loads for one chunk into named reg set S (ping-pong).
#define LOADSET(S, base) {                                                \
    const char* p_ = (base);                                              \
    S##0 = *(const f16x8*)(p_);                                           \
    S##1 = *(const f16x8*)(p_ + 1024);                                    \
    S##2 = *(const f16x8*)(p_ + 2048);                                    \
    S##3 = *(const f16x8*)(p_ + 3072);                                    \
    S##4 = *(const f16x8*)(p_ + 4096);                                    \
    S##5 = *(const f16x8*)(p_ + 5120);                                    \
    S##6 = *(const f16x8*)(p_ + 6144);                                    \
    S##7 = *(const f16x8*)(p_ + 7168); }

// vals[r] (own sample s32, row SROW(r)) -> B-frags (k-contig), hi + unscaled lo.
#define BUILD_FRAGS(F0, F1, L0, L1, V) {                                  \
    u32 owh[8], owl[8];                                                   \
    _Pragma("unroll")                                                     \
    for (int i_ = 0; i_ < 8; ++i_) {                                      \
        float v0_ = (V)[2*i_], v1_ = (V)[2*i_ + 1];                       \
        auto hp_ = __builtin_amdgcn_cvt_pkrtz(v0_, v1_);                  \
        owh[i_] = __builtin_bit_cast(u32, hp_);                           \
        float r0_ = v0_ - (float)hp_[0];                                  \
        float r1_ = v1_ - (float)hp_[1];                                  \
        auto lp_ = __builtin_amdgcn_cvt_pkrtz(r0_, r1_);                  \
        owl[i_] = __builtin_bit_cast(u32, lp_);                          \
    }                                                                     \
    {                                                                     \
        u32 a0_ = owh[0], b0_ = owh[2]; plswap(a0_, b0_);                 \
        u32 a1_ = owh[1], b1_ = owh[3]; plswap(a1_, b1_);                 \
        F0 = __builtin_bit_cast(f16x8, (u32x4){a0_, a1_, b0_, b1_});      \
        u32 c0_ = owh[4], d0_ = owh[6]; plswap(c0_, d0_);                 \
        u32 c1_ = owh[5], d1_ = owh[7]; plswap(c1_, d1_);                 \
        F1 = __builtin_bit_cast(f16x8, (u32x4){c0_, c1_, d0_, d1_});      \
        u32 e0_ = owl[0], f0_ = owl[2]; plswap(e0_, f0_);                 \
        u32 e1_ = owl[1], f1_ = owl[3]; plswap(e1_, f1_);                 \
        L0 = __builtin_bit_cast(f16x8, (u32x4){e0_, e1_, f0_, f1_});      \
        u32 g0_ = owl[4], h0_ = owl[6]; plswap(g0_, h0_);                 \
        u32 g1_ = owl[5], h1_ = owl[7]; plswap(g1_, h1_);                 \
        L1 = __builtin_bit_cast(f16x8, (u32x4){g0_, g1_, h0_, h1_});      \
    } }

#define MFMA(d, a, b, c) d = __builtin_amdgcn_mfma_f32_32x32x16_f16(a, b, c, 0, 0, 0)

// fwd chunk: H^T(+b1) via 6 MFMAs into hm; relu+mask; Y^T += 6 MFMAs
#define FWD_CHUNK(S, c) {                                                 \
    f32x16 hm;                                                            \
    { const float4* bp_ = (const float4*)(sB1p + (c) * 32 + gh * 16);     \
      float4 t0_ = bp_[0], t1_ = bp_[1], t2_ = bp_[2], t3_ = bp_[3];      \
      hm[0]=t0_.x; hm[1]=t0_.y; hm[2]=t0_.z; hm[3]=t0_.w;                 \
      hm[4]=t1_.x; hm[5]=t1_.y; hm[6]=t1_.z; hm[7]=t1_.w;                 \
      hm[8]=t2_.x; hm[9]=t2_.y; hm[10]=t2_.z; hm[11]=t2_.w;               \
      hm[12]=t3_.x; hm[13]=t3_.y; hm[14]=t3_.z; hm[15]=t3_.w; }           \
    MFMA(hm, S##0, za0h, hm); MFMA(hm, S##0, za0l, hm);                   \
    MFMA(hm, S##2, za0h, hm); MFMA(hm, S##1, za1h, hm);                   \
    MFMA(hm, S##1, za1l, hm); MFMA(hm, S##3, za1h, hm);                   \
    float rv_[16]; u32 mb_ = 0;                                           \
    _Pragma("unroll")                                                     \
    for (int r_ = 0; r_ < 16; ++r_) {                                     \
        float h_ = hm[r_];                                                \
        if (h_ > 0.f) mb_ |= (1u << r_);                                  \
        rv_[r_] = fmaxf(h_, 0.f);                                         \
    }                                                                     \
    mkb[(c) * 64 + ln] = (u16)mb_;                                        \
    f16x8 rf0_, rf1_, rl0_, rl1_;                                         \
    BUILD_FRAGS(rf0_, rf1_, rl0_, rl1_, rv_)                              \
    MFMA(ym, S##4, rf0_, ym); MFMA(ym, S##4, rl0_, ym);                   \
    MFMA(ym, S##6, rf0_, ym); MFMA(ym, S##5, rf1_, ym);                   \
    MFMA(ym, S##5, rl1_, ym); MFMA(ym, S##7, rf1_, ym); }

// bwd chunk: GR^T via 6 MFMAs; mask*(-gr); K^T += 6 MFMAs
#define BWD_CHUNK(S, c) {                                                 \
    f32x16 gm;                                                            \
    _Pragma("unroll")                                                     \
    for (int r_ = 0; r_ < 16; ++r_) gm[r_] = 0.f;                         \
    MFMA(gm, S##0, gf0, gm); MFMA(gm, S##0, gl0, gm);                     \
    MFMA(gm, S##2, gf0, gm); MFMA(gm, S##1, gf1, gm);                     \
    MFMA(gm, S##1, gl1, gm); MFMA(gm, S##3, gf1, gm);                     \
    u32 mb_ = mkb[(c) * 64 + ln];                                         \
    float mv_[16];                                                        \
    _Pragma("unroll")                                                     \
    for (int r_ = 0; r_ < 16; ++r_) {                                     \
        float g_ = gm[r_];                                                \
        mv_[r_] = (mb_ & (1u << r_)) ? -g_ : 0.f;                         \
    }                                                                     \
    f16x8 mf0_, mf1_, ml0_, ml1_;                                         \
    BUILD_FRAGS(mf0_, mf1_, ml0_, ml1_, mv_)                              \
    MFMA(km, S##4, mf0_, km); MFMA(km, S##4, ml0_, km);                   \
    MFMA(km, S##6, mf0_, km); MFMA(km, S##5, mf1_, km);                   \
    MFMA(km, S##5, ml1_, km); MFMA(km, S##7, mf1_, km); }

__global__ __launch_bounds__(TPB, 2)
void hopfield_mfma3(const float* __restrict__ x,
                    const float* __restrict__ b1,
                    const float* __restrict__ b2,
                    const f16* __restrict__ ws,
                    float* __restrict__ out) {
    __shared__ __align__(16) float sB1p[HID];   // 4 KB, SROW-permuted bias
    __shared__ __align__(16) float sB2p[UNITS];
    __shared__ u16 sMsk[WPB][NCH * 64];         // 16 KB relu masks (per-wave)

    const int tid = threadIdx.x;
    const int wv = tid >> 6, ln = tid & 63;
    const int s32 = ln & 31, gh = ln >> 5;

    for (int i = tid; i < HID; i += TPB) {
        int c = i >> 5, g_ = (i >> 4) & 1, r = i & 15;
        sB1p[i] = b1[c * 32 + ((r & 3) + ((r >> 2) << 3) + (g_ << 2))];
    }
    if (tid < UNITS) {
        int g_ = (tid >> 4) & 1, r = tid & 15;
        sB2p[tid] = b2[(r & 3) + ((r >> 2) << 3) + (g_ << 2)];
    }
    __syncthreads();          // the only block-wide barrier

    u16* mkb = &sMsk[wv][0];

    const long samp = (long)blockIdx.x * SPB + wv * 32 + s32;
    float zb[16], acc[16], zcv[16];
    {
        const float* xr = x + samp * UNITS;
        #pragma unroll
        for (int q = 0; q < 4; ++q) {
            float4 v = *(const float4*)(xr + 8 * q + 4 * gh);
            zb[4*q+0] = v.x; zb[4*q+1] = v.y; zb[4*q+2] = v.z; zb[4*q+3] = v.w;
        }
    }

    const char* pfwd = (const char*)ws + (size_t)ln * 16;
    const char* pbwd = pfwd + BWDOFF;

    f16x8 A0, A1, A2, A3, A4, A5, A6, A7;
    f16x8 B0, B1, B2, B3, B4, B5, B6, B7;
    LOADSET(A, pfwd)          // prologue: fwd chunk 0 in flight

    #pragma unroll 1
    for (int step = 0; step < 10; ++step) {
        #pragma unroll
        for (int r = 0; r < 16; ++r) { acc[r] = 0.f; zcv[r] = zb[r]; }

        #pragma unroll 1
        for (int sub = 0; sub < 4; ++sub) {
            f16x8 za0h, za1h, za0l, za1l;
            BUILD_FRAGS(za0h, za1h, za0l, za1l, zcv)

            f32x16 ym;
            {   // Y^T accumulator init with b2 (SROW order)
                const float4* bp = (const float4*)(sB2p + gh * 16);
                float4 v0 = bp[0], v1 = bp[1], v2 = bp[2], v3 = bp[3];
                ym[0]=v0.x; ym[1]=v0.y; ym[2]=v0.z; ym[3]=v0.w;
                ym[4]=v1.x; ym[5]=v1.y; ym[6]=v1.z; ym[7]=v1.w;
                ym[8]=v2.x; ym[9]=v2.y; ym[10]=v2.z; ym[11]=v2.w;
                ym[12]=v3.x; ym[13]=v3.y; ym[14]=v3.z; ym[15]=v3.w;
            }

            // ============ forward: 32 chunks, ping-pong direct-global ======
            #pragma unroll 1
            for (int c = 0; c < NCH - 2; c += 2) {
                LOADSET(B, pfwd + (c + 1) * 8192)
                FWD_CHUNK(A, c)
                LOADSET(A, pfwd + (c + 2) * 8192)
                FWD_CHUNK(B, c + 1)
            }
            LOADSET(B, pfwd + (NCH - 1) * 8192)
            FWD_CHUNK(A, NCH - 2)
            LOADSET(A, pbwd)              // prefetch bwd chunk 0
            FWD_CHUNK(B, NCH - 1)

            // ============ G = 8*Y/||Y|| — register-local ===================
            f16x8 gf0, gf1, gl0, gl1;
            {
                float yv[16], t = 0.f;
                #pragma unroll
                for (int r = 0; r < 16; ++r) {
                    float y = ym[r];
                    yv[r] = y;
                    t = fmaf(y, y, t);
                }
                t += __shfl_xor(t, 32, 64);
                float s8 = 8.0f * rsqrtf(t);
                #pragma unroll
                for (int r = 0; r < 16; ++r) yv[r] *= s8;
                BUILD_FRAGS(gf0, gf1, gl0, gl1, yv)
            }

            f32x16 km;
            #pragma unroll
            for (int r = 0; r < 16; ++r) km[r] = 0.f;

            // ============ backward: 32 chunks, ping-pong ===================
            #pragma unroll 1
            for (int c = 0; c < NCH - 2; c += 2) {
                LOADSET(B, pbwd + (c + 1) * 8192)
                BWD_CHUNK(A, c)
                LOADSET(A, pbwd + (c + 2) * 8192)
                BWD_CHUNK(B, c + 1)
            }
            LOADSET(B, pbwd + (NCH - 1) * 8192)
            BWD_CHUNK(A, NCH - 2)
            LOADSET(A, pfwd)              // prefetch next fwd chunk 0
            BWD_CHUNK(B, NCH - 1)

            // ============ RK4 bookkeeping ==================================
            {
                float aw = (sub == 0 || sub == 3) ? 1.f : 2.f;
                float cw = (sub == 2) ? 0.1f : 0.05f;
                #pragma unroll
                for (int r = 0; r < 16; ++r) {
                    float kv = km[r];
                    acc[r] += aw * kv;
                    if (sub < 3) zcv[r] = fmaf(cw, kv, zb[r]);
                }
            }
        } // sub

        #pragma unroll
        for (int r = 0; r < 16; ++r) zb[r] = fmaf(0.1f / 6.0f, acc[r], zb[r]);
    } // step

    {
        float* orow = out + samp * UNITS;
        #pragma unroll
        for (int q = 0; q < 4; ++q) {
            float4 v;
            v.x = zb[4*q+0]; v.y = zb[4*q+1]; v.z = zb[4*q+2]; v.w = zb[4*q+3];
            *(float4*)(orow + 8 * q + 4 * gh) = v;
        }
    }
}

extern "C" void kernel_launch(void* const* d_in, const int* in_sizes, int n_in,
                              void* d_out, int out_size, void* d_ws, size_t ws_size,
                              hipStream_t stream) {
    const float* x  = (const float*)d_in[0];
    const float* W1 = (const float*)d_in[1];
    const float* b1 = (const float*)d_in[2];
    const float* W2 = (const float*)d_in[3];
    const float* b2 = (const float*)d_in[4];
    float* out = (float*)d_out;
    f16* ws = (f16*)d_ws;   // 512 KB
    hipLaunchKernelGGL(prep_weights, dim3(128), dim3(256), 0, stream, W1, W2, ws);
    hipLaunchKernelGGL(hopfield_mfma3, dim3(NBLK), dim3(TPB), 0, stream,
                       x, b1, b2, ws, out);
}

// Round 13
// 4211.845 us; speedup vs baseline: 9.0095x; 1.1193x over previous
//
#include <hip/hip_runtime.h>

typedef _Float16 f16;
typedef __attribute__((ext_vector_type(8))) _Float16 f16x8;
typedef __attribute__((ext_vector_type(16))) float f32x16;
typedef __attribute__((ext_vector_type(2))) unsigned int u32x2;
typedef __attribute__((ext_vector_type(4))) unsigned int u32x4;
typedef unsigned int u32;
typedef unsigned short u16;

#define UNITS 32
#define HID   1024
#define NCH   32      // 32 chunks of 32 j
#define TPB   256     // 4 waves
#define WPB   4
#define SPB   128     // samples per block
#define NBLK  1024
#define BWDOFF 262144

static_assert(NBLK * SPB == 131072, "grid covers batch");

// d_ws (512 KB): two regions (FWD @0, BWD @256KB), each
// [c:32][load:8][lane:64][16B], load = slice*2 + ks.
// FWD slices: 0/1 = W1^T hi/lo (A of H^T=W1^T@Z^T), 2/3 = W2^T hi/lo (A of Y^T)
// BWD slices: 0/1 = W2  hi/lo (A of GR^T=W2@G^T),   2/3 = W1  hi/lo (A of K^T)
// lo residuals UNSCALED: lo = f16(v - hi); all 3 split MFMAs share one C.
__global__ void prep_weights(const float* __restrict__ W1,
                             const float* __restrict__ W2,
                             f16* __restrict__ ws) {
    int idx = blockIdx.x * 256 + threadIdx.x;   // (c, jl, u)
    int c = idx >> 10, rem = idx & 1023;
    int jl = rem >> 5, u = rem & 31;
    int j = c * 32 + jl;
    float w1 = W1[u * HID + j];
    f16 h1 = (f16)w1;
    f16 l1 = (f16)(w1 - (float)h1);
    float w2 = W2[j * UNITS + u];
    f16 h2 = (f16)w2;
    f16 l2 = (f16)(w2 - (float)h2);
    char* p = (char*)ws;
    auto off = [&](int region, int slice, int row, int k) {
        int ks = k >> 4;
        int lane = row + ((k >> 3) & 1) * 32;
        return region + c * 8192 + (slice * 2 + ks) * 1024 + lane * 16 + (k & 7) * 2;
    };
    *(f16*)(p + off(0, 0, jl, u))      = h1;
    *(f16*)(p + off(0, 1, jl, u))      = l1;
    *(f16*)(p + off(0, 2, u, jl))      = h2;
    *(f16*)(p + off(0, 3, u, jl))      = l2;
    *(f16*)(p + off(BWDOFF, 0, jl, u)) = h2;
    *(f16*)(p + off(BWDOFF, 1, jl, u)) = l2;
    *(f16*)(p + off(BWDOFF, 2, u, jl)) = h1;
    *(f16*)(p + off(BWDOFF, 3, u, jl)) = l1;
}

__device__ __forceinline__ void plswap(u32& a, u32& b) {
    u32x2 r = __builtin_amdgcn_permlane32_swap(a, b, false, false);
    a = r.x; b = r.y;
}

// r = v - f32(f16 half of h): single v_fma_mix_f32 (f16 source, f32 math)
__device__ __forceinline__ float fmix_lo(u32 h, float v, float fone) {
    float r;
    asm("v_fma_mix_f32 %0, -%1, %2, %3 op_sel_hi:[1,0,0]"
        : "=v"(r) : "v"(h), "v"(fone), "v"(v));
    return r;
}
__device__ __forceinline__ float fmix_hi(u32 h, float v, float fone) {
    float r;
    asm("v_fma_mix_f32 %0, -%1, %2, %3 op_sel:[1,0,0] op_sel_hi:[1,0,0]"
        : "=v"(r) : "v"(h), "v"(fone), "v"(v));
    return r;
}

// 4 direct global 16B loads (half chunk) into named reg set S (ping-pong).
#define LOADSET4(S, base) {                                               \
    const char* p_ = (base);                                              \
    S##0 = *(const f16x8*)(p_);                                           \
    S##1 = *(const f16x8*)(p_ + 1024);                                    \
    S##2 = *(const f16x8*)(p_ + 2048);                                    \
    S##3 = *(const f16x8*)(p_ + 3072); }

// vals[r] (own sample s32, row SROW(r)) -> B-frags (k-contig), hi + unscaled lo.
#define BUILD_FRAGS(F0, F1, L0, L1, V) {                                  \
    u32 owh[8], owl[8];                                                   \
    _Pragma("unroll")                                                     \
    for (int i_ = 0; i_ < 8; ++i_) {                                      \
        float v0_ = (V)[2*i_], v1_ = (V)[2*i_ + 1];                       \
        auto hp_ = __builtin_amdgcn_cvt_pkrtz(v0_, v1_);                  \
        owh[i_] = __builtin_bit_cast(u32, hp_);                           \
        float r0_ = fmix_lo(owh[i_], v0_, fone);                          \
        float r1_ = fmix_hi(owh[i_], v1_, fone);                          \
        auto lp_ = __builtin_amdgcn_cvt_pkrtz(r0_, r1_);                  \
        owl[i_] = __builtin_bit_cast(u32, lp_);                           \
    }                                                                     \
    {                                                                     \
        u32 a0_ = owh[0], b0_ = owh[2]; plswap(a0_, b0_);                 \
        u32 a1_ = owh[1], b1_ = owh[3]; plswap(a1_, b1_);                 \
        F0 = __builtin_bit_cast(f16x8, (u32x4){a0_, a1_, b0_, b1_});      \
        u32 c0_ = owh[4], d0_ = owh[6]; plswap(c0_, d0_);                 \
        u32 c1_ = owh[5], d1_ = owh[7]; plswap(c1_, d1_);                 \
        F1 = __builtin_bit_cast(f16x8, (u32x4){c0_, c1_, d0_, d1_});      \
        u32 e0_ = owl[0], f0_ = owl[2]; plswap(e0_, f0_);                 \
        u32 e1_ = owl[1], f1_ = owl[3]; plswap(e1_, f1_);                 \
        L0 = __builtin_bit_cast(f16x8, (u32x4){e0_, e1_, f0_, f1_});      \
        u32 g0_ = owl[4], h0_ = owl[6]; plswap(g0_, h0_);                 \
        u32 g1_ = owl[5], h1_ = owl[7]; plswap(g1_, h1_);                 \
        L1 = __builtin_bit_cast(f16x8, (u32x4){g0_, g1_, h0_, h1_});      \
    } }

#define MFMA(d, a, b, c) d = __builtin_amdgcn_mfma_f32_32x32x16_f16(a, b, c, 0, 0, 0)

__global__ __launch_bounds__(TPB, 2)
__attribute__((amdgpu_waves_per_eu(2, 2)))
void hopfield_mfma4(const float* __restrict__ x,
                    const float* __restrict__ b1,
                    const float* __restrict__ b2,
                    const f16* __restrict__ ws,
                    float* __restrict__ out) {
    __shared__ __align__(16) float sB1p[HID];   // 4 KB, SROW-permuted bias
    __shared__ __align__(16) float sB2p[UNITS];
    __shared__ u16 sMsk[WPB][NCH * 64];         // 16 KB relu masks (per-wave)

    const int tid = threadIdx.x;
    const int wv = tid >> 6, ln = tid & 63;
    const int s32 = ln & 31, gh = ln >> 5;

    for (int i = tid; i < HID; i += TPB) {
        int c = i >> 5, g_ = (i >> 4) & 1, r = i & 15;
        sB1p[i] = b1[c * 32 + ((r & 3) + ((r >> 2) << 3) + (g_ << 2))];
    }
    if (tid < UNITS) {
        int g_ = (tid >> 4) & 1, r = tid & 15;
        sB2p[tid] = b2[(r & 3) + ((r >> 2) << 3) + (g_ << 2)];
    }
    __syncthreads();          // the only block-wide barrier

    u16* mkb = &sMsk[wv][0];
    const float fone = 1.0f;

    const long samp = (long)blockIdx.x * SPB + wv * 32 + s32;
    float zb[16], acc[16];
    {
        const float* xr = x + samp * UNITS;
        #pragma unroll
        for (int q = 0; q < 4; ++q) {
            float4 v = *(const float4*)(xr + 8 * q + 4 * gh);
            zb[4*q+0] = v.x; zb[4*q+1] = v.y; zb[4*q+2] = v.z; zb[4*q+3] = v.w;
        }
    }

    f32x16 zeros;
    #pragma unroll
    for (int r = 0; r < 16; ++r) zeros[r] = 0.f;

    const char* pfwd = (const char*)ws + (size_t)ln * 16;
    const char* pbwd = pfwd + BWDOFF;

    f16x8 P0, P1, P2, P3;     // GEMM-1 weights of current chunk
    f16x8 Q0, Q1, Q2, Q3;     // GEMM-2 weights of current chunk
    LOADSET4(P, pfwd)         // prologue: fwd chunk 0 G1 in flight

    f16x8 za0h, za1h, za0l, za1l;
    BUILD_FRAGS(za0h, za1h, za0l, za1l, zb)

    #pragma unroll 1
    for (int step = 0; step < 10; ++step) {
        #pragma unroll
        for (int r = 0; r < 16; ++r) acc[r] = 0.f;

        #pragma unroll 1
        for (int sub = 0; sub < 4; ++sub) {
            f32x16 ym;
            {   // Y^T accumulator init with b2 (SROW order)
                const float4* bp = (const float4*)(sB2p + gh * 16);
                float4 v0 = bp[0], v1 = bp[1], v2 = bp[2], v3 = bp[3];
                ym[0]=v0.x; ym[1]=v0.y; ym[2]=v0.z; ym[3]=v0.w;
                ym[4]=v1.x; ym[5]=v1.y; ym[6]=v1.z; ym[7]=v1.w;
                ym[8]=v2.x; ym[9]=v2.y; ym[10]=v2.z; ym[11]=v2.w;
                ym[12]=v3.x; ym[13]=v3.y; ym[14]=v3.z; ym[15]=v3.w;
            }

            // ============ forward: H^T(+b1 at relu), R^T, Y^T +=  ==========
            #pragma unroll 1
            for (int c = 0; c < NCH; ++c) {
                LOADSET4(Q, pfwd + c * 8192 + 4096)     // G2 weights of c
                f32x16 hm;
                MFMA(hm, P0, za0h, zeros);
                MFMA(hm, P0, za0l, hm);
                MFMA(hm, P2, za0h, hm);
                MFMA(hm, P1, za1h, hm);
                MFMA(hm, P1, za1l, hm);
                MFMA(hm, P3, za1h, hm);

                float rv[16]; u32 mb = 0;
                {
                    const float4* bp = (const float4*)(sB1p + c * 32 + gh * 16);
                    float4 b0 = bp[0], b1v = bp[1], b2v = bp[2], b3 = bp[3];
                    float bv[16] = {b0.x,b0.y,b0.z,b0.w, b1v.x,b1v.y,b1v.z,b1v.w,
                                    b2v.x,b2v.y,b2v.z,b2v.w, b3.x,b3.y,b3.z,b3.w};
                    #pragma unroll
                    for (int r = 0; r < 16; ++r) {
                        float s = hm[r] + bv[r];
                        if (s > 0.f) mb |= (1u << r);
                        rv[r] = fmaxf(s, 0.f);
                    }
                }
                mkb[c * 64 + ln] = (u16)mb;

                f16x8 rf0, rf1, rl0, rl1;
                BUILD_FRAGS(rf0, rf1, rl0, rl1, rv)
                LOADSET4(P, (c < NCH - 1) ? (pfwd + (c + 1) * 8192) : pbwd)
                MFMA(ym, Q0, rf0, ym); MFMA(ym, Q0, rl0, ym);
                MFMA(ym, Q2, rf0, ym); MFMA(ym, Q1, rf1, ym);
                MFMA(ym, Q1, rl1, ym); MFMA(ym, Q3, rf1, ym);
            }

            // ============ G = 8*Y/||Y|| — register-local ===================
            f16x8 gf0, gf1, gl0, gl1;
            {
                float yv[16], t = 0.f;
                #pragma unroll
                for (int r = 0; r < 16; ++r) {
                    float y = ym[r];
                    yv[r] = y;
                    t = fmaf(y, y, t);
                }
                t += __shfl_xor(t, 32, 64);
                float s8 = 8.0f * rsqrtf(t);
                #pragma unroll
                for (int r = 0; r < 16; ++r) yv[r] *= s8;
                BUILD_FRAGS(gf0, gf1, gl0, gl1, yv)
            }

            f32x16 km;
            #pragma unroll
            for (int r = 0; r < 16; ++r) km[r] = 0.f;

            // ============ backward: GR^T, M = -mask*GR, K^T += ============
            #pragma unroll 1
            for (int c = 0; c < NCH; ++c) {
                LOADSET4(Q, pbwd + c * 8192 + 4096)     // G2 weights of c
                f32x16 gm;
                MFMA(gm, P0, gf0, zeros);
                MFMA(gm, P0, gl0, gm);
                MFMA(gm, P2, gf0, gm);
                MFMA(gm, P1, gf1, gm);
                MFMA(gm, P1, gl1, gm);
                MFMA(gm, P3, gf1, gm);

                u32 mb = mkb[c * 64 + ln];
                float mv[16];
                #pragma unroll
                for (int r = 0; r < 16; ++r) {
                    float g = gm[r];
                    mv[r] = (mb & (1u << r)) ? -g : 0.f;
                }

                f16x8 mf0, mf1, ml0, ml1;
                BUILD_FRAGS(mf0, mf1, ml0, ml1, mv)
                LOADSET4(P, (c < NCH - 1) ? (pbwd + (c + 1) * 8192) : pfwd)
                MFMA(km, Q0, mf0, km); MFMA(km, Q0, ml0, km);
                MFMA(km, Q2, mf0, km); MFMA(km, Q1, mf1, km);
                MFMA(km, Q1, ml1, km); MFMA(km, Q3, mf1, km);
            }

            // ============ RK4 bookkeeping + fused za rebuild ==============
            if (sub < 3) {
                float aw = (sub == 0) ? 1.f : 2.f;
                float cw = (sub == 2) ? 0.1f : 0.05f;
                float vz[16];
                #pragma unroll
                for (int r = 0; r < 16; ++r) {
                    float kv = km[r];
                    acc[r] += aw * kv;
                    vz[r] = fmaf(cw, kv, zb[r]);
                }
                BUILD_FRAGS(za0h, za1h, za0l, za1l, vz)
            } else {
                #pragma unroll
                for (int r = 0; r < 16; ++r) acc[r] += km[r];
            }
        } // sub

        #pragma unroll
        for (int r = 0; r < 16; ++r) zb[r] = fmaf(0.1f / 6.0f, acc[r], zb[r]);
        BUILD_FRAGS(za0h, za1h, za0l, za1l, zb)   // za for next step
    } // step

    {
        float* orow = out + samp * UNITS;
        #pragma unroll
        for (int q = 0; q < 4; ++q) {
            float4 v;
            v.x = zb[4*q+0]; v.y = zb[4*q+1]; v.z = zb[4*q+2]; v.w = zb[4*q+3];
            *(float4*)(orow + 8 * q + 4 * gh) = v;
        }
    }
}

extern "C" void kernel_launch(void* const* d_in, const int* in_sizes, int n_in,
                              void* d_out, int out_size, void* d_ws, size_t ws_size,
                              hipStream_t stream) {
    const float* x  = (const float*)d_in[0];
    const float* W1 = (const float*)d_in[1];
    const float* b1 = (const float*)d_in[2];
    const float* W2 = (const float*)d_in[3];
    const float* b2 = (const float*)d_in[4];
    float* out = (float*)d_out;
    f16* ws = (f16*)d_ws;   // 512 KB
    hipLaunchKernelGGL(prep_weights, dim3(128), dim3(256), 0, stream, W1, W2, ws);
    hipLaunchKernelGGL(hopfield_mfma4, dim3(NBLK), dim3(TPB), 0, stream,
                       x, b1, b2, ws, out);
}